// Round 2
// baseline (2202.465 us; speedup 1.0000x reference)
//
#include <hip/hip_runtime.h>
#include <math.h>

#define BATCH 2
#define NTOK  1024
#define EDIM  512
#define NHEAD 8
#define KVCH  1536
#define TKV   3072   // 3*NTOK

// ---------------- workspace layout (float offsets) ----------------
constexpr size_t OFF_QC  = 0;                 // [B,N,KVC]  3,145,728
constexpr size_t OFF_KC  = 3145728;
constexpr size_t OFF_VC  = 6291456;
constexpr size_t OFF_ATT = 9437184;           // [B,KVC,KVC] 4,718,592
constexpr size_t OFF_KVS = OFF_QC;            // reuse (QC dead after ATT)
constexpr size_t OFF_K   = OFF_KC;            // reuse
constexpr size_t OFF_V   = OFF_VC;            // reuse
constexpr size_t OFF_QB  = 14155776;          // [B,N,E] 1,048,576
constexpr size_t OFF_CTX = 15204352;          // [B,N,E] 1,048,576
constexpr size_t OFF_CH  = 16252928;          // 4 doubles (8 floats)
constexpr size_t OFF_GK  = 16252936;          // 16*4096
constexpr size_t OFF_SK  = 16318472;          // 16*64
constexpr size_t OFF_GQ  = 16319496;          // 16*4096
constexpr size_t OFF_SQ  = 16385032;          // 16*64
constexpr size_t OFF_SV  = 16386056;          // 16

#define MICRO16(S, a, b) \
    S[0][0]=fmaf(a.x,b.x,S[0][0]); S[0][1]=fmaf(a.x,b.y,S[0][1]); S[0][2]=fmaf(a.x,b.z,S[0][2]); S[0][3]=fmaf(a.x,b.w,S[0][3]); \
    S[1][0]=fmaf(a.y,b.x,S[1][0]); S[1][1]=fmaf(a.y,b.y,S[1][1]); S[1][2]=fmaf(a.y,b.z,S[1][2]); S[1][3]=fmaf(a.y,b.w,S[1][3]); \
    S[2][0]=fmaf(a.z,b.x,S[2][0]); S[2][1]=fmaf(a.z,b.y,S[2][1]); S[2][2]=fmaf(a.z,b.z,S[2][2]); S[2][3]=fmaf(a.z,b.w,S[2][3]); \
    S[3][0]=fmaf(a.w,b.x,S[3][0]); S[3][1]=fmaf(a.w,b.y,S[3][1]); S[3][2]=fmaf(a.w,b.z,S[3][2]); S[3][3]=fmaf(a.w,b.w,S[3][3]);

// ---------------- generic C = A @ B^T (64x64 tile, fp32) ----------------
// A: [M,K] lda, B: [N,K] ldb, C: [M,N] ldc. M,N %64==0, K %16==0.
// z batching: zb=z/zmod, zj=z%zmod; ptr += zb*s?0 + zj*s?1
__global__ __launch_bounds__(256) void gemm_abT(
    const float* __restrict__ A, const float* __restrict__ B, float* __restrict__ C,
    int K, int lda, int ldb, int ldc,
    int zmod, long sA0, long sA1, long sB0, long sB1, long sC0, long sC1)
{
    __shared__ float As[16][68];
    __shared__ float Bs[16][68];
    int z = blockIdx.z;
    int zb = z / zmod, zj = z % zmod;
    A += (size_t)zb * sA0 + (size_t)zj * sA1;
    B += (size_t)zb * sB0 + (size_t)zj * sB1;
    C += (size_t)zb * sC0 + (size_t)zj * sC1;
    const int m0 = blockIdx.y << 6, n0 = blockIdx.x << 6;
    const int tid = threadIdx.x;
    const int tx = tid & 15, ty = tid >> 4;
    const int lk = (tid & 3) << 2;   // k sub-offset 0,4,8,12
    const int lr = tid >> 2;         // row 0..63
    float acc[4][4] = {};
    for (int k0 = 0; k0 < K; k0 += 16) {
        float4 av = *(const float4*)(A + (size_t)(m0 + lr) * lda + k0 + lk);
        float4 bv = *(const float4*)(B + (size_t)(n0 + lr) * ldb + k0 + lk);
        __syncthreads();
        As[lk+0][lr]=av.x; As[lk+1][lr]=av.y; As[lk+2][lr]=av.z; As[lk+3][lr]=av.w;
        Bs[lk+0][lr]=bv.x; Bs[lk+1][lr]=bv.y; Bs[lk+2][lr]=bv.z; Bs[lk+3][lr]=bv.w;
        __syncthreads();
        #pragma unroll
        for (int k = 0; k < 16; ++k) {
            float4 a = *(const float4*)&As[k][ty << 2];
            float4 b = *(const float4*)&Bs[k][tx << 2];
            MICRO16(acc, a, b)
        }
    }
    #pragma unroll
    for (int i = 0; i < 4; ++i) {
        *(float4*)(C + (size_t)(m0 + (ty<<2) + i) * ldc + n0 + (tx<<2)) =
            make_float4(acc[i][0], acc[i][1], acc[i][2], acc[i][3]);
    }
}

// ---------------- C[c,d] = sum_n A[n,c] * B[n,d]  (A^T B) ----------------
__global__ __launch_bounds__(256) void gemm_aTb(
    const float* __restrict__ A, const float* __restrict__ B, float* __restrict__ C,
    int K, int lda, int ldb, int ldc, long sA, long sB, long sC)
{
    __shared__ float As[16][68];
    __shared__ float Bs[16][68];
    int z = blockIdx.z;
    A += (size_t)z * sA; B += (size_t)z * sB; C += (size_t)z * sC;
    const int c0 = blockIdx.y << 6, d0 = blockIdx.x << 6;
    const int tid = threadIdx.x;
    const int tx = tid & 15, ty = tid >> 4;
    const int lc = tid & 63, ln = tid >> 6;   // ln 0..3
    float acc[4][4] = {};
    for (int n0 = 0; n0 < K; n0 += 16) {
        float av[4], bv[4];
        #pragma unroll
        for (int i = 0; i < 4; ++i) {
            av[i] = A[(size_t)(n0 + ln + 4*i) * lda + c0 + lc];
            bv[i] = B[(size_t)(n0 + ln + 4*i) * ldb + d0 + lc];
        }
        __syncthreads();
        #pragma unroll
        for (int i = 0; i < 4; ++i) { As[ln + 4*i][lc] = av[i]; Bs[ln + 4*i][lc] = bv[i]; }
        __syncthreads();
        #pragma unroll
        for (int k = 0; k < 16; ++k) {
            float4 a = *(const float4*)&As[k][ty << 2];
            float4 b = *(const float4*)&Bs[k][tx << 2];
            MICRO16(acc, a, b)
        }
    }
    #pragma unroll
    for (int i = 0; i < 4; ++i) {
        *(float4*)(C + (size_t)(c0 + (ty<<2) + i) * ldc + d0 + (tx<<2)) =
            make_float4(acc[i][0], acc[i][1], acc[i][2], acc[i][3]);
    }
}

// ---------------- channel attn mean/var over [KVC,KVC] per batch ----------------
__global__ __launch_bounds__(256) void chan_meanvar(const float* __restrict__ ATT, double* __restrict__ ST)
{
    size_t base = (size_t)blockIdx.y * ((size_t)KVCH * KVCH) + (size_t)blockIdx.x * 1024;
    int tid = threadIdx.x;
    float4 v = *(const float4*)(ATT + base + tid * 4);
    double s  = (double)v.x + (double)v.y + (double)v.z + (double)v.w;
    double s2 = (double)v.x*v.x + (double)v.y*v.y + (double)v.z*v.z + (double)v.w*v.w;
    #pragma unroll
    for (int m = 32; m; m >>= 1) { s += __shfl_xor(s, m); s2 += __shfl_xor(s2, m); }
    __shared__ double ls[4], ls2[4];
    int w = tid >> 6;
    if ((tid & 63) == 0) { ls[w] = s; ls2[w] = s2; }
    __syncthreads();
    if (tid == 0) {
        atomicAdd(&ST[2*blockIdx.y],   ls[0]+ls[1]+ls[2]+ls[3]);
        atomicAdd(&ST[2*blockIdx.y+1], ls2[0]+ls2[1]+ls2[2]+ls2[3]);
    }
}

// ---------------- channel softmax row-wise, in place ----------------
__global__ __launch_bounds__(256) void chan_softmax(float* __restrict__ ATT, const double* __restrict__ ST)
{
    int b = blockIdx.y;
    float* p = ATT + (size_t)b * KVCH * KVCH + (size_t)blockIdx.x * KVCH;
    double cnt = (double)KVCH * (double)KVCH;
    double mean = ST[2*b] / cnt;
    double var  = ST[2*b+1] / cnt - mean * mean;
    float sc = (float)(1.0 / sqrt(var + 1e-5));
    int tid = threadIdx.x;
    float x[6];
    #pragma unroll
    for (int k = 0; k < 6; ++k) x[k] = p[tid + (k << 8)] * sc;
    float mx = fmaxf(fmaxf(fmaxf(x[0],x[1]),fmaxf(x[2],x[3])),fmaxf(x[4],x[5]));
    #pragma unroll
    for (int m = 32; m; m >>= 1) mx = fmaxf(mx, __shfl_xor(mx, m));
    __shared__ float red[4];
    int w = tid >> 6;
    if ((tid & 63) == 0) red[w] = mx;
    __syncthreads();
    mx = fmaxf(fmaxf(red[0],red[1]), fmaxf(red[2],red[3]));
    __syncthreads();
    float e[6]; float sum = 0.f;
    #pragma unroll
    for (int k = 0; k < 6; ++k) { e[k] = __expf(x[k] - mx); sum += e[k]; }
    #pragma unroll
    for (int m = 32; m; m >>= 1) sum += __shfl_xor(sum, m);
    if ((tid & 63) == 0) red[w] = sum;
    __syncthreads();
    sum = red[0]+red[1]+red[2]+red[3];
    float inv = 1.0f / sum;
    #pragma unroll
    for (int k = 0; k < 6; ++k) p[tid + (k << 8)] = e[k] * inv;
}

// ---------------- per (b,h) 64x64 Gram + column sums ----------------
__global__ __launch_bounds__(256) void gram64(const float* __restrict__ X, int T,
                                              float* __restrict__ G, float* __restrict__ CS)
{
    int bh = blockIdx.x;
    int b = bh >> 3, h = bh & 7;
    const float* Xb = X + (size_t)b * T * EDIM + h * 64;
    int rows = T / gridDim.y;
    int t0 = blockIdx.y * rows;
    __shared__ float Xs[4][64];
    int tid = threadIdx.x;
    int i0 = (tid >> 4) << 2, j0 = (tid & 15) << 2;
    float acc[4][4] = {};
    float cs = 0.f;
    for (int t = t0; t < t0 + rows; t += 4) {
        __syncthreads();
        int r = tid >> 6, c = tid & 63;
        Xs[r][c] = Xb[(size_t)(t + r) * EDIM + c];
        __syncthreads();
        #pragma unroll
        for (int rr = 0; rr < 4; ++rr) {
            float xi0=Xs[rr][i0], xi1=Xs[rr][i0+1], xi2=Xs[rr][i0+2], xi3=Xs[rr][i0+3];
            float xj0=Xs[rr][j0], xj1=Xs[rr][j0+1], xj2=Xs[rr][j0+2], xj3=Xs[rr][j0+3];
            acc[0][0]=fmaf(xi0,xj0,acc[0][0]); acc[0][1]=fmaf(xi0,xj1,acc[0][1]); acc[0][2]=fmaf(xi0,xj2,acc[0][2]); acc[0][3]=fmaf(xi0,xj3,acc[0][3]);
            acc[1][0]=fmaf(xi1,xj0,acc[1][0]); acc[1][1]=fmaf(xi1,xj1,acc[1][1]); acc[1][2]=fmaf(xi1,xj2,acc[1][2]); acc[1][3]=fmaf(xi1,xj3,acc[1][3]);
            acc[2][0]=fmaf(xi2,xj0,acc[2][0]); acc[2][1]=fmaf(xi2,xj1,acc[2][1]); acc[2][2]=fmaf(xi2,xj2,acc[2][2]); acc[2][3]=fmaf(xi2,xj3,acc[2][3]);
            acc[3][0]=fmaf(xi3,xj0,acc[3][0]); acc[3][1]=fmaf(xi3,xj1,acc[3][1]); acc[3][2]=fmaf(xi3,xj2,acc[3][2]); acc[3][3]=fmaf(xi3,xj3,acc[3][3]);
        }
        if (tid < 64) cs += Xs[0][tid] + Xs[1][tid] + Xs[2][tid] + Xs[3][tid];
    }
    float* Gp = G + (size_t)bh * 4096;
    #pragma unroll
    for (int i = 0; i < 4; ++i)
        #pragma unroll
        for (int j = 0; j < 4; ++j)
            atomicAdd(&Gp[(i0 + i) * 64 + j0 + j], acc[i][j]);
    if (tid < 64) atomicAdd(&CS[bh * 64 + tid], cs);
}

// ---------------- per (b,h) scale = rsqrt(var(QK^T)+eps) ----------------
__global__ __launch_bounds__(256) void spatial_scale(
    const float* __restrict__ GQ, const float* __restrict__ GK,
    const float* __restrict__ SQm, const float* __restrict__ SKm, float* __restrict__ SV)
{
    int bh = blockIdx.x, tid = threadIdx.x;
    double e2 = 0.0;
    for (int i = tid; i < 4096; i += 256)
        e2 += (double)GQ[bh*4096 + i] * (double)GK[bh*4096 + i];
    double mm = 0.0;
    if (tid < 64) mm = (double)SQm[bh*64 + tid] * (double)SKm[bh*64 + tid];
    #pragma unroll
    for (int m = 32; m; m >>= 1) { e2 += __shfl_xor(e2, m); mm += __shfl_xor(mm, m); }
    __shared__ double se[4], sm[4];
    int w = tid >> 6;
    if ((tid & 63) == 0) { se[w] = e2; sm[w] = mm; }
    __syncthreads();
    if (tid == 0) {
        double cnt = (double)NTOK * (double)TKV;
        double E2 = (se[0]+se[1]+se[2]+se[3]) / cnt;
        double M  = (sm[0]+sm[1]+sm[2]+sm[3]) / cnt;
        double var = E2 - M * M;
        SV[bh] = (float)(1.0 / sqrt(var + 1e-5));
    }
}

// ---------------- flash attention: O = softmax(s * Q K^T) V ----------------
__global__ __launch_bounds__(256) void flash_attn(
    const float* __restrict__ Q, const float* __restrict__ K, const float* __restrict__ V,
    const float* __restrict__ SV, float* __restrict__ O)
{
    __shared__ float Qs[64][68], Ks[64][68], Vs[64][68], Ps[64][68];
    int bh = blockIdx.y, b = bh >> 3, h = bh & 7;
    int n0 = blockIdx.x << 6;
    int tid = threadIdx.x, tx = tid & 15, ty = tid >> 4;
    float sc = SV[bh];
    const float* Qb = Q + (size_t)b * NTOK * EDIM + (size_t)n0 * EDIM + h * 64;
    const float* Kb = K + (size_t)b * TKV * EDIM + h * 64;
    const float* Vb = V + (size_t)b * TKV * EDIM + h * 64;
    #pragma unroll
    for (int it = 0; it < 4; ++it) {
        int idx4 = (it << 8) + tid;
        int q = idx4 >> 4, d4 = (idx4 & 15) << 2;
        float4 v = *(const float4*)(Qb + (size_t)q * EDIM + d4);
        Qs[d4+0][q]=v.x; Qs[d4+1][q]=v.y; Qs[d4+2][q]=v.z; Qs[d4+3][q]=v.w;
    }
    float mreg[4], lreg[4], acc[4][4] = {};
    #pragma unroll
    for (int i = 0; i < 4; ++i) { mreg[i] = -1e30f; lreg[i] = 0.f; }
    for (int t0 = 0; t0 < TKV; t0 += 64) {
        __syncthreads();
        #pragma unroll
        for (int it = 0; it < 4; ++it) {
            int idx4 = (it << 8) + tid;
            int t = idx4 >> 4, d4 = (idx4 & 15) << 2;
            float4 kv = *(const float4*)(Kb + (size_t)(t0 + t) * EDIM + d4);
            Ks[d4+0][t]=kv.x; Ks[d4+1][t]=kv.y; Ks[d4+2][t]=kv.z; Ks[d4+3][t]=kv.w;
            float4 vv = *(const float4*)(Vb + (size_t)(t0 + t) * EDIM + d4);
            *(float4*)&Vs[t][d4] = vv;
        }
        __syncthreads();
        float S[4][4] = {};
        #pragma unroll
        for (int k = 0; k < 64; ++k) {
            float4 a = *(const float4*)&Qs[k][ty << 2];
            float4 b2 = *(const float4*)&Ks[k][tx << 2];
            MICRO16(S, a, b2)
        }
        #pragma unroll
        for (int i = 0; i < 4; ++i) {
            float tm = fmaxf(fmaxf(S[i][0], S[i][1]), fmaxf(S[i][2], S[i][3]));
            tm = fmaxf(tm, __shfl_xor(tm, 1, 16));
            tm = fmaxf(tm, __shfl_xor(tm, 2, 16));
            tm = fmaxf(tm, __shfl_xor(tm, 4, 16));
            tm = fmaxf(tm, __shfl_xor(tm, 8, 16));
            float mnew = fmaxf(mreg[i], sc * tm);
            float alpha = __expf(mreg[i] - mnew);
            float p0 = __expf(fmaf(sc, S[i][0], -mnew));
            float p1 = __expf(fmaf(sc, S[i][1], -mnew));
            float p2 = __expf(fmaf(sc, S[i][2], -mnew));
            float p3 = __expf(fmaf(sc, S[i][3], -mnew));
            float ps = p0 + p1 + p2 + p3;
            ps += __shfl_xor(ps, 1, 16);
            ps += __shfl_xor(ps, 2, 16);
            ps += __shfl_xor(ps, 4, 16);
            ps += __shfl_xor(ps, 8, 16);
            lreg[i] = lreg[i] * alpha + ps;
            mreg[i] = mnew;
            acc[i][0]*=alpha; acc[i][1]*=alpha; acc[i][2]*=alpha; acc[i][3]*=alpha;
            *(float4*)&Ps[(ty<<2)+i][tx<<2] = make_float4(p0, p1, p2, p3);
        }
        __syncthreads();
        #pragma unroll
        for (int t = 0; t < 64; ++t) {
            float4 bv = *(const float4*)&Vs[t][tx << 2];
            float4 pv = make_float4(Ps[(ty<<2)+0][t], Ps[(ty<<2)+1][t],
                                    Ps[(ty<<2)+2][t], Ps[(ty<<2)+3][t]);
            MICRO16(acc, pv, bv)
        }
    }
    float* Ob = O + (size_t)b * NTOK * EDIM + (size_t)n0 * EDIM + h * 64;
    #pragma unroll
    for (int i = 0; i < 4; ++i) {
        float inv = 1.f / lreg[i];
        *(float4*)(Ob + (size_t)((ty<<2)+i) * EDIM + (tx<<2)) =
            make_float4(acc[i][0]*inv, acc[i][1]*inv, acc[i][2]*inv, acc[i][3]*inv);
    }
}

extern "C" void kernel_launch(void* const* d_in, const int* in_sizes, int n_in,
                              void* d_out, int out_size, void* d_ws, size_t ws_size,
                              hipStream_t stream)
{
    const float* embs[3] = {(const float*)d_in[0], (const float*)d_in[1], (const float*)d_in[2]};
    const float* embC = (const float*)d_in[3];
    const float* Wq[3] = {(const float*)d_in[4], (const float*)d_in[5], (const float*)d_in[6]};
    const float* Wk  = (const float*)d_in[7];
    const float* Wv  = (const float*)d_in[8];
    const float* WqC = (const float*)d_in[9];
    const float* WkC = (const float*)d_in[10];
    const float* WvC = (const float*)d_in[11];
    const float* Wo[3] = {(const float*)d_in[12], (const float*)d_in[13], (const float*)d_in[14]};
    float* out = (float*)d_out;
    float* ws = (float*)d_ws;

    float* QC  = ws + OFF_QC;
    float* KC  = ws + OFF_KC;
    float* VC  = ws + OFF_VC;
    float* ATT = ws + OFF_ATT;
    float* KVS = ws + OFF_KVS;
    float* Kb  = ws + OFF_K;
    float* Vb  = ws + OFF_V;
    float* QB  = ws + OFF_QB;
    float* CTX = ws + OFF_CTX;
    double* CH = (double*)(ws + OFF_CH);
    float* GK  = ws + OFF_GK;
    float* SK  = ws + OFF_SK;
    float* GQ  = ws + OFF_GQ;
    float* SQm = ws + OFF_SQ;
    float* SV  = ws + OFF_SV;

    dim3 blk(256);
    // zero CH stats + GK + SK (contiguous)
    hipMemsetAsync(ws + OFF_CH, 0, (8 + 65536 + 1024) * sizeof(float), stream);

    // channel projections: [2048,1536] = embC_flat @ W^T
    gemm_abT<<<dim3(24, 32, 1), blk, 0, stream>>>(embC, WqC, QC, KVCH, KVCH, KVCH, KVCH, 1, 0,0,0,0,0,0);
    gemm_abT<<<dim3(24, 32, 1), blk, 0, stream>>>(embC, WkC, KC, KVCH, KVCH, KVCH, KVCH, 1, 0,0,0,0,0,0);
    gemm_abT<<<dim3(24, 32, 1), blk, 0, stream>>>(embC, WvC, VC, KVCH, KVCH, KVCH, KVCH, 1, 0,0,0,0,0,0);
    // ATT[b] = QC[b]^T @ KC[b]   [KVC,KVC], contraction over tokens
    gemm_aTb<<<dim3(24, 24, 2), blk, 0, stream>>>(QC, KC, ATT, NTOK, KVCH, KVCH, KVCH,
        (long)NTOK*KVCH, (long)NTOK*KVCH, (long)KVCH*KVCH);
    chan_meanvar<<<dim3(2304, 2), blk, 0, stream>>>(ATT, CH);
    chan_softmax<<<dim3(1536, 2), blk, 0, stream>>>(ATT, CH);
    // KVS[b, j*N+n, e] = sum_d SIM[b, j*E+e, d] * VC[b, n, d]
    gemm_abT<<<dim3(8, 16, 6), blk, 0, stream>>>(VC, ATT, KVS, KVCH, KVCH, KVCH, EDIM, 3,
        (long)NTOK*KVCH, 0, (long)KVCH*KVCH, (long)EDIM*KVCH, (long)TKV*EDIM, (long)NTOK*EDIM);
    // K/V projections: [6144,512]
    gemm_abT<<<dim3(8, 96, 1), blk, 0, stream>>>(KVS, Wk, Kb, EDIM, EDIM, EDIM, EDIM, 1, 0,0,0,0,0,0);
    gemm_abT<<<dim3(8, 96, 1), blk, 0, stream>>>(KVS, Wv, Vb, EDIM, EDIM, EDIM, EDIM, 1, 0,0,0,0,0,0);
    gram64<<<dim3(16, 8), blk, 0, stream>>>(Kb, TKV, GK, SK);

    for (int st = 0; st < 3; ++st) {
        gemm_abT<<<dim3(8, 32, 1), blk, 0, stream>>>(embs[st], Wq[st], QB, EDIM, EDIM, EDIM, EDIM, 1, 0,0,0,0,0,0);
        hipMemsetAsync(GQ, 0, (65536 + 1024) * sizeof(float), stream);
        gram64<<<dim3(16, 8), blk, 0, stream>>>(QB, NTOK, GQ, SQm);
        spatial_scale<<<dim3(16), blk, 0, stream>>>(GQ, GK, SQm, SK, SV);
        flash_attn<<<dim3(16, 16), blk, 0, stream>>>(QB, Kb, Vb, SV, CTX);
        gemm_abT<<<dim3(8, 32, 1), blk, 0, stream>>>(CTX, Wo[st], out + (size_t)st * BATCH * NTOK * EDIM,
            EDIM, EDIM, EDIM, EDIM, 1, 0,0,0,0,0,0);
    }
}

// Round 3
// 1766.560 us; speedup vs baseline: 1.2468x; 1.2468x over previous
//
#include <hip/hip_runtime.h>
#include <math.h>

#define NTOK 1024
#define EDIM 512
#define KVCH 1536
#define TKV  3072

typedef __bf16 bf16x8 __attribute__((ext_vector_type(8)));
typedef float f32x4 __attribute__((ext_vector_type(4)));
#define MFMA16(a,b,c) __builtin_amdgcn_mfma_f32_16x16x32_bf16(a,b,c,0,0,0)

__device__ __forceinline__ ushort f2bf(float f){
    uint u = __float_as_uint(f);
    u += 0x7FFFu + ((u>>16)&1u);
    return (ushort)(u>>16);
}
__device__ __forceinline__ float bf2f(ushort h){ return __uint_as_float(((uint)h)<<16); }
__device__ __forceinline__ bf16x8 ldsb8(const ushort* p){ return *(const bf16x8*)p; }

// ---------------- batched fp32 -> bf16 hi/lo split ----------------
#define NCVT 15
struct CvtJobs { const float* src[NCVT]; ushort* hi[NCVT]; ushort* lo[NCVT]; int n[NCVT]; };

__global__ __launch_bounds__(256) void cvt_hilo(CvtJobs J)
{
    int a = blockIdx.y;
    int i = (blockIdx.x*256 + threadIdx.x)*4;
    if (i >= J.n[a]) return;
    float4 v = *(const float4*)(J.src[a] + i);
    ushort4 h, l;
    h.x=f2bf(v.x); l.x=f2bf(v.x-bf2f(h.x));
    h.y=f2bf(v.y); l.y=f2bf(v.y-bf2f(h.y));
    h.z=f2bf(v.z); l.z=f2bf(v.z-bf2f(h.z));
    h.w=f2bf(v.w); l.w=f2bf(v.w-bf2f(h.w));
    *(ushort4*)(J.hi[a]+i) = h;
    *(ushort4*)(J.lo[a]+i) = l;
}

// ---------------- MFMA GEMM: C = A @ B^T with bf16x3 split ----------------
// A: [M,K] hi/lo u16, B: [N,K] hi/lo u16. 128x128 tile, BK=32, 4 waves.
// Outputs (any non-null): Cf fp32 [M,N]; Chi/Clo bf16 [M,N]; Cthi/Ctlo bf16 transposed [N-major]: elem (m,n) at n*ldct+m.
__global__ __launch_bounds__(256) void mgemm(
    const ushort* __restrict__ Ahi, const ushort* __restrict__ Alo,
    const ushort* __restrict__ Bhi, const ushort* __restrict__ Blo,
    float* __restrict__ Cf, ushort* __restrict__ Chi, ushort* __restrict__ Clo,
    ushort* __restrict__ Cthi, ushort* __restrict__ Ctlo,
    int K, int lda, int ldb, int ldc, int ldct,
    int zmod, long sA0, long sA1, long sB0, long sB1, long sC0, long sC1)
{
    __shared__ ushort Ah[128*40], Al[128*40], Bh[128*40], Bl[128*40];
    const int tid = threadIdx.x;
    const int z = blockIdx.z, zb = z / zmod, zj = z - zb*zmod;
    const size_t aoff = (size_t)zb*sA0 + (size_t)zj*sA1;
    const size_t boff = (size_t)zb*sB0 + (size_t)zj*sB1;
    const size_t coff = (size_t)zb*sC0 + (size_t)zj*sC1;
    const int m0 = blockIdx.y<<7, n0 = blockIdx.x<<7;
    const int wave = tid>>6, lane = tid&63;
    const int wr = wave>>1, wc = wave&1;
    const int fr = lane&15, fq = lane>>4;
    f32x4 acc[4][4];
    #pragma unroll
    for (int i=0;i<4;++i)
        #pragma unroll
        for (int j=0;j<4;++j) acc[i][j] = (f32x4){0.f,0.f,0.f,0.f};

    const int r0 = tid>>2;        // staging row (it=0)
    const int sg = (tid&3)<<3;    // k-seg in u16
    for (int k0=0; k0<K; k0+=32) {
        uint4 vah[2], val2[2], vbh[2], vbl[2];
        #pragma unroll
        for (int it=0; it<2; ++it) {
            int row = r0 + (it<<6);
            size_t ga = aoff + (size_t)(m0+row)*lda + k0 + sg;
            size_t gb = boff + (size_t)(n0+row)*ldb + k0 + sg;
            vah[it]  = *(const uint4*)(Ahi+ga);
            val2[it] = *(const uint4*)(Alo+ga);
            vbh[it]  = *(const uint4*)(Bhi+gb);
            vbl[it]  = *(const uint4*)(Blo+gb);
        }
        __syncthreads();
        #pragma unroll
        for (int it=0; it<2; ++it) {
            int lo = (r0 + (it<<6))*40 + sg;
            *(uint4*)&Ah[lo] = vah[it];
            *(uint4*)&Al[lo] = val2[it];
            *(uint4*)&Bh[lo] = vbh[it];
            *(uint4*)&Bl[lo] = vbl[it];
        }
        __syncthreads();
        bf16x8 fah[4], fal[4];
        #pragma unroll
        for (int m=0;m<4;++m) {
            int o = (wr*64 + m*16 + fr)*40 + fq*8;
            fah[m] = ldsb8(&Ah[o]); fal[m] = ldsb8(&Al[o]);
        }
        #pragma unroll
        for (int n=0;n<4;++n) {
            int o = (wc*64 + n*16 + fr)*40 + fq*8;
            bf16x8 fbh = ldsb8(&Bh[o]), fbl = ldsb8(&Bl[o]);
            #pragma unroll
            for (int m=0;m<4;++m) {
                acc[m][n] = MFMA16(fah[m], fbh, acc[m][n]);
                acc[m][n] = MFMA16(fah[m], fbl, acc[m][n]);
                acc[m][n] = MFMA16(fal[m], fbh, acc[m][n]);
            }
        }
    }
    #pragma unroll
    for (int m=0;m<4;++m) {
        #pragma unroll
        for (int n=0;n<4;++n) {
            int row = m0 + wr*64 + m*16 + fq*4;
            int col = n0 + wc*64 + n*16 + fr;
            f32x4 v = acc[m][n];
            if (Cf) {
                #pragma unroll
                for (int r=0;r<4;++r) Cf[coff + (size_t)(row+r)*ldc + col] = v[r];
            }
            if (Chi) {
                #pragma unroll
                for (int r=0;r<4;++r) {
                    ushort hh = f2bf(v[r]);
                    size_t o = coff + (size_t)(row+r)*ldc + col;
                    Chi[o] = hh; Clo[o] = f2bf(v[r]-bf2f(hh));
                }
            }
            if (Cthi) {
                ushort4 h4, l4;
                #pragma unroll
                for (int r=0;r<4;++r) {
                    ushort hh = f2bf(v[r]);
                    ((ushort*)&h4)[r] = hh;
                    ((ushort*)&l4)[r] = f2bf(v[r]-bf2f(hh));
                }
                size_t o = coff + (size_t)col*ldct + row;
                *(ushort4*)(Cthi+o) = h4;
                *(ushort4*)(Ctlo+o) = l4;
            }
        }
    }
}

// ---------------- channel attn mean/var over [KVC,KVC] per batch ----------------
__global__ __launch_bounds__(256) void chan_meanvar(const float* __restrict__ ATT, double* __restrict__ ST)
{
    size_t base = (size_t)blockIdx.y * ((size_t)KVCH * KVCH) + (size_t)blockIdx.x * 1024;
    int tid = threadIdx.x;
    float4 v = *(const float4*)(ATT + base + tid * 4);
    double s  = (double)v.x + (double)v.y + (double)v.z + (double)v.w;
    double s2 = (double)v.x*v.x + (double)v.y*v.y + (double)v.z*v.z + (double)v.w*v.w;
    #pragma unroll
    for (int m = 32; m; m >>= 1) { s += __shfl_xor(s, m); s2 += __shfl_xor(s2, m); }
    __shared__ double ls[4], ls2[4];
    int w = tid >> 6;
    if ((tid & 63) == 0) { ls[w] = s; ls2[w] = s2; }
    __syncthreads();
    if (tid == 0) {
        atomicAdd(&ST[2*blockIdx.y],   ls[0]+ls[1]+ls[2]+ls[3]);
        atomicAdd(&ST[2*blockIdx.y+1], ls2[0]+ls2[1]+ls2[2]+ls2[3]);
    }
}

// ---------------- channel softmax row-wise -> bf16 hi/lo ----------------
__global__ __launch_bounds__(256) void chan_softmax(const float* __restrict__ ATT, const double* __restrict__ ST,
                                                    ushort* __restrict__ Shi, ushort* __restrict__ Slo)
{
    int b = blockIdx.y;
    size_t ro = (size_t)b * KVCH * KVCH + (size_t)blockIdx.x * KVCH;
    const float* p = ATT + ro;
    ushort* ph = Shi + ro;
    ushort* pl = Slo + ro;
    double cnt = (double)KVCH * (double)KVCH;
    double mean = ST[2*b] / cnt;
    double var  = ST[2*b+1] / cnt - mean * mean;
    float sc = (float)(1.0 / sqrt(var + 1e-5));
    int tid = threadIdx.x;
    float x[6];
    #pragma unroll
    for (int k = 0; k < 6; ++k) x[k] = p[tid + (k << 8)] * sc;
    float mx = fmaxf(fmaxf(fmaxf(x[0],x[1]),fmaxf(x[2],x[3])),fmaxf(x[4],x[5]));
    #pragma unroll
    for (int m = 32; m; m >>= 1) mx = fmaxf(mx, __shfl_xor(mx, m));
    __shared__ float red[4];
    int w = tid >> 6;
    if ((tid & 63) == 0) red[w] = mx;
    __syncthreads();
    mx = fmaxf(fmaxf(red[0],red[1]), fmaxf(red[2],red[3]));
    __syncthreads();
    float e[6]; float sum = 0.f;
    #pragma unroll
    for (int k = 0; k < 6; ++k) { e[k] = __expf(x[k] - mx); sum += e[k]; }
    #pragma unroll
    for (int m = 32; m; m >>= 1) sum += __shfl_xor(sum, m);
    if ((tid & 63) == 0) red[w] = sum;
    __syncthreads();
    sum = red[0]+red[1]+red[2]+red[3];
    float inv = 1.0f / sum;
    #pragma unroll
    for (int k = 0; k < 6; ++k) {
        float pv = e[k] * inv;
        ushort hh = f2bf(pv);
        ph[tid + (k << 8)] = hh;
        pl[tid + (k << 8)] = f2bf(pv - bf2f(hh));
    }
}

// ---------------- per (b,h) 64x64 Gram + column sums (z-batched) ----------------
__global__ __launch_bounds__(256) void gram64(const float* __restrict__ X, int T,
                                              float* __restrict__ G, float* __restrict__ CS,
                                              long sX, long sG, long sCS)
{
    int zz = blockIdx.z;
    X += (size_t)zz * sX; G += (size_t)zz * sG; CS += (size_t)zz * sCS;
    int bh = blockIdx.x;
    int b = bh >> 3, h = bh & 7;
    const float* Xb = X + (size_t)b * T * EDIM + h * 64;
    int rows = T / gridDim.y;
    int t0 = blockIdx.y * rows;
    __shared__ float Xs[4][64];
    int tid = threadIdx.x;
    int i0 = (tid >> 4) << 2, j0 = (tid & 15) << 2;
    float acc[4][4] = {};
    float cs = 0.f;
    for (int t = t0; t < t0 + rows; t += 4) {
        __syncthreads();
        int r = tid >> 6, c = tid & 63;
        Xs[r][c] = Xb[(size_t)(t + r) * EDIM + c];
        __syncthreads();
        #pragma unroll
        for (int rr = 0; rr < 4; ++rr) {
            float xi0=Xs[rr][i0], xi1=Xs[rr][i0+1], xi2=Xs[rr][i0+2], xi3=Xs[rr][i0+3];
            float xj0=Xs[rr][j0], xj1=Xs[rr][j0+1], xj2=Xs[rr][j0+2], xj3=Xs[rr][j0+3];
            acc[0][0]=fmaf(xi0,xj0,acc[0][0]); acc[0][1]=fmaf(xi0,xj1,acc[0][1]); acc[0][2]=fmaf(xi0,xj2,acc[0][2]); acc[0][3]=fmaf(xi0,xj3,acc[0][3]);
            acc[1][0]=fmaf(xi1,xj0,acc[1][0]); acc[1][1]=fmaf(xi1,xj1,acc[1][1]); acc[1][2]=fmaf(xi1,xj2,acc[1][2]); acc[1][3]=fmaf(xi1,xj3,acc[1][3]);
            acc[2][0]=fmaf(xi2,xj0,acc[2][0]); acc[2][1]=fmaf(xi2,xj1,acc[2][1]); acc[2][2]=fmaf(xi2,xj2,acc[2][2]); acc[2][3]=fmaf(xi2,xj3,acc[2][3]);
            acc[3][0]=fmaf(xi3,xj0,acc[3][0]); acc[3][1]=fmaf(xi3,xj1,acc[3][1]); acc[3][2]=fmaf(xi3,xj2,acc[3][2]); acc[3][3]=fmaf(xi3,xj3,acc[3][3]);
        }
        if (tid < 64) cs += Xs[0][tid] + Xs[1][tid] + Xs[2][tid] + Xs[3][tid];
    }
    float* Gp = G + (size_t)bh * 4096;
    #pragma unroll
    for (int i = 0; i < 4; ++i)
        #pragma unroll
        for (int j = 0; j < 4; ++j)
            atomicAdd(&Gp[(i0 + i) * 64 + j0 + j], acc[i][j]);
    if (tid < 64) atomicAdd(&CS[bh * 64 + tid], cs);
}

// ---------------- per (st,b,h) scale = rsqrt(var(QK^T)+eps) ----------------
__global__ __launch_bounds__(256) void spatial_scale(
    const float* __restrict__ GQ, const float* __restrict__ GK,
    const float* __restrict__ SQm, const float* __restrict__ SKm, float* __restrict__ SVo)
{
    int st = blockIdx.y, bh = blockIdx.x, tid = threadIdx.x;
    const float* gq = GQ + (size_t)st*65536 + bh*4096;
    const float* gk = GK + bh*4096;
    double e2 = 0.0;
    for (int i = tid; i < 4096; i += 256)
        e2 += (double)gq[i] * (double)gk[i];
    double mm = 0.0;
    if (tid < 64) mm = (double)SQm[(size_t)st*1024 + bh*64 + tid] * (double)SKm[bh*64 + tid];
    #pragma unroll
    for (int m = 32; m; m >>= 1) { e2 += __shfl_xor(e2, m); mm += __shfl_xor(mm, m); }
    __shared__ double se[4], sm[4];
    int w = tid >> 6;
    if ((tid & 63) == 0) { se[w] = e2; sm[w] = mm; }
    __syncthreads();
    if (tid == 0) {
        double cnt = (double)NTOK * (double)TKV;
        double E2 = (se[0]+se[1]+se[2]+se[3]) / cnt;
        double M  = (sm[0]+sm[1]+sm[2]+sm[3]) / cnt;
        double var = E2 - M * M;
        SVo[st*16+bh] = (float)(1.0 / sqrt(var + 1e-5));
    }
}

// ---------------- V transpose per head: [B,TKV,E] -> [B,H,64,TKV] (bf16 hi/lo) ----------------
__global__ __launch_bounds__(256) void vtrans(const ushort* __restrict__ Vhi, const ushort* __restrict__ Vlo,
                                              ushort* __restrict__ Thi, ushort* __restrict__ Tlo)
{
    __shared__ ushort th[64*72], tl[64*72];
    int t0 = blockIdx.x<<6, h = blockIdx.y, b = blockIdx.z;
    int tid = threadIdx.x;
    #pragma unroll
    for (int it=0; it<2; ++it) {
        int idx = (it<<8)+tid, row = idx>>3, seg = (idx&7)<<3;
        size_t g = (size_t)(b*TKV + t0 + row)*EDIM + h*64 + seg;
        *(uint4*)&th[row*72+seg] = *(const uint4*)(Vhi+g);
        *(uint4*)&tl[row*72+seg] = *(const uint4*)(Vlo+g);
    }
    __syncthreads();
    #pragma unroll
    for (int it=0; it<2; ++it) {
        int idx = (it<<8)+tid, d = idx>>3, ts = (idx&7)<<3;
        ushort oh[8], ol[8];
        #pragma unroll
        for (int j=0;j<8;++j) { oh[j] = th[(ts+j)*72 + d]; ol[j] = tl[(ts+j)*72 + d]; }
        size_t g = ((size_t)(b*8+h)*64 + d)*TKV + t0 + ts;
        *(uint4*)(Thi+g) = *(uint4*)oh;
        *(uint4*)(Tlo+g) = *(uint4*)ol;
    }
}

// ---------------- MFMA flash attention (bf16x3): O = softmax(sc*QK^T)V ----------------
__global__ __launch_bounds__(256) void flash_mfma(
    const ushort* __restrict__ Qhi, const ushort* __restrict__ Qlo,
    const ushort* __restrict__ Khi, const ushort* __restrict__ Klo,
    const ushort* __restrict__ VThi, const ushort* __restrict__ VTlo,
    const float* __restrict__ SV,
    ushort* __restrict__ Ohi, ushort* __restrict__ Olo)
{
    __shared__ ushort Qh[4608], Ql[4608], Kh[4608], Kl[4608], Vh[4608], Vl[4608];
    __shared__ ushort Ph[4][1152], Pl[4][1152];
    const int st = blockIdx.z, bh = blockIdx.y, b = bh>>3, h = bh&7;
    const int n0 = blockIdx.x<<6;
    const int tid = threadIdx.x, wave = tid>>6, lane = tid&63;
    const int fr = lane&15, fq = lane>>4;
    const float sc = SV[st*16 + bh];
    const size_t qb = (size_t)st*(2048*512) + (size_t)(b*1024 + n0)*512 + h*64;
    #pragma unroll
    for (int it=0; it<2; ++it) {
        int idx = (it<<8)+tid, row = idx>>3, seg = (idx&7)<<3;
        *(uint4*)&Qh[row*72+seg] = *(const uint4*)(Qhi + qb + (size_t)row*512 + seg);
        *(uint4*)&Ql[row*72+seg] = *(const uint4*)(Qlo + qb + (size_t)row*512 + seg);
    }
    f32x4 accO[4]; float mr[4], lr[4];
    #pragma unroll
    for (int i=0;i<4;++i){ accO[i]=(f32x4){0.f,0.f,0.f,0.f}; mr[i]=-1e30f; lr[i]=0.f; }
    const size_t kb = (size_t)(b*TKV)*512 + h*64;
    const size_t vb = ((size_t)(b*8+h)*64)*TKV;
    for (int t0=0; t0<TKV; t0+=64) {
        #pragma unroll
        for (int it=0; it<2; ++it) {
            int idx=(it<<8)+tid, row=idx>>3, seg=(idx&7)<<3;
            size_t gk = kb + (size_t)(t0+row)*512 + seg;
            *(uint4*)&Kh[row*72+seg] = *(const uint4*)(Khi+gk);
            *(uint4*)&Kl[row*72+seg] = *(const uint4*)(Klo+gk);
            size_t gv = vb + (size_t)row*TKV + t0 + seg;
            *(uint4*)&Vh[row*72+seg] = *(const uint4*)(VThi+gv);
            *(uint4*)&Vl[row*72+seg] = *(const uint4*)(VTlo+gv);
        }
        __syncthreads();
        f32x4 s[4];
        #pragma unroll
        for (int i=0;i<4;++i) s[i]=(f32x4){0.f,0.f,0.f,0.f};
        #pragma unroll
        for (int ks=0; ks<2; ++ks) {
            int qo = (wave*16+fr)*72 + ks*32 + fq*8;
            bf16x8 qh = ldsb8(&Qh[qo]), ql = ldsb8(&Ql[qo]);
            #pragma unroll
            for (int nf=0; nf<4; ++nf) {
                int ko = (nf*16+fr)*72 + ks*32 + fq*8;
                bf16x8 kh = ldsb8(&Kh[ko]), kl = ldsb8(&Kl[ko]);
                s[nf] = MFMA16(qh, kh, s[nf]);
                s[nf] = MFMA16(qh, kl, s[nf]);
                s[nf] = MFMA16(ql, kh, s[nf]);
            }
        }
        #pragma unroll
        for (int reg=0; reg<4; ++reg) {
            float p[4];
            float tm = fmaxf(fmaxf(s[0][reg],s[1][reg]), fmaxf(s[2][reg],s[3][reg]));
            tm = fmaxf(tm, __shfl_xor(tm,1,16));
            tm = fmaxf(tm, __shfl_xor(tm,2,16));
            tm = fmaxf(tm, __shfl_xor(tm,4,16));
            tm = fmaxf(tm, __shfl_xor(tm,8,16));
            float mn = fmaxf(mr[reg], sc*tm);
            float al = __expf(mr[reg]-mn);
            mr[reg] = mn;
            float ps = 0.f;
            #pragma unroll
            for (int nf=0;nf<4;++nf){ p[nf] = __expf(fmaf(sc, s[nf][reg], -mn)); ps += p[nf]; }
            ps += __shfl_xor(ps,1,16); ps += __shfl_xor(ps,2,16);
            ps += __shfl_xor(ps,4,16); ps += __shfl_xor(ps,8,16);
            lr[reg] = lr[reg]*al + ps;
            #pragma unroll
            for (int df=0;df<4;++df) accO[df][reg] *= al;
            int prow = (fq*4+reg)*72;
            #pragma unroll
            for (int nf=0;nf<4;++nf) {
                ushort hh = f2bf(p[nf]);
                Ph[wave][prow + nf*16 + fr] = hh;
                Pl[wave][prow + nf*16 + fr] = f2bf(p[nf]-bf2f(hh));
            }
        }
        #pragma unroll
        for (int ks=0; ks<2; ++ks) {
            int po = fr*72 + ks*32 + fq*8;
            bf16x8 ph = ldsb8(&Ph[wave][po]), pl = ldsb8(&Pl[wave][po]);
            #pragma unroll
            for (int df=0; df<4; ++df) {
                int vo = (df*16+fr)*72 + ks*32 + fq*8;
                bf16x8 vh = ldsb8(&Vh[vo]), vl = ldsb8(&Vl[vo]);
                accO[df] = MFMA16(ph, vh, accO[df]);
                accO[df] = MFMA16(ph, vl, accO[df]);
                accO[df] = MFMA16(pl, vh, accO[df]);
            }
        }
        __syncthreads();
    }
    #pragma unroll
    for (int reg=0; reg<4; ++reg) {
        float inv = 1.f/lr[reg];
        int row = n0 + wave*16 + fq*4 + reg;
        #pragma unroll
        for (int df=0; df<4; ++df) {
            float v = accO[df][reg]*inv;
            size_t o = (size_t)st*(2048*512) + (size_t)(b*1024+row)*512 + h*64 + df*16 + fr;
            ushort hh = f2bf(v);
            Ohi[o] = hh; Olo[o] = f2bf(v-bf2f(hh));
        }
    }
}

// ---------------- workspace layout (byte offsets) ----------------
constexpr size_t OFF_CH  = 0;           // 8 doubles
constexpr size_t OFF_GK  = 64;          // 65536 f32
constexpr size_t OFF_SK  = 262208;      // 1024 f32
constexpr size_t OFF_GQ  = 266304;      // 3*65536 f32
constexpr size_t OFF_SQM = 1052736;     // 3*1024 f32
constexpr size_t OFF_SV  = 1065024;     // 48 f32
constexpr size_t ZERO_BYTES = 1065024;
constexpr size_t S0 = 1065472;          // W8: 8 x 1 MB (hi 512KB + lo 512KB)
constexpr size_t S1 = S0 + 8388608;     // WC: 3 x 9437184; overlays: ATT f32; Kb hilo; Vb hilo
constexpr size_t S2 = S1 + 28311552;    // embC hilo; overlays: KVS hilo; VT hilo
constexpr size_t S3 = S2 + 12582912;    // emb123 hilo
constexpr size_t S4 = S3 + 12582912;    // QCt hilo; overlays: SIMhi(+into S5); QB hilo
constexpr size_t S5 = S4 + 12582912;    // KCt hilo; overlays: CTX hilo
constexpr size_t S6 = S5 + 12582912;    // VC hilo; overlays: Kb f32; QB f32
// total = S6 + 12582912 = 100,680,192 bytes (~96 MB)

extern "C" void kernel_launch(void* const* d_in, const int* in_sizes, int n_in,
                              void* d_out, int out_size, void* d_ws, size_t ws_size,
                              hipStream_t stream)
{
    const float* emb[3] = {(const float*)d_in[0], (const float*)d_in[1], (const float*)d_in[2]};
    const float* embC = (const float*)d_in[3];
    const float* WqF[3] = {(const float*)d_in[4], (const float*)d_in[5], (const float*)d_in[6]};
    const float* WkF  = (const float*)d_in[7];
    const float* WvF  = (const float*)d_in[8];
    const float* WCF[3] = {(const float*)d_in[9], (const float*)d_in[10], (const float*)d_in[11]};
    const float* WoF[3] = {(const float*)d_in[12], (const float*)d_in[13], (const float*)d_in[14]};
    float* out = (float*)d_out;
    char* ws = (char*)d_ws;

    auto U16 = [&](size_t off)->ushort* { return (ushort*)(ws + off); };
    auto F32 = [&](size_t off)->float*  { return (float*)(ws + off); };

    double* CH = (double*)(ws + OFF_CH);
    float *GK = F32(OFF_GK), *SK = F32(OFF_SK), *GQ = F32(OFF_GQ), *SQm = F32(OFF_SQM), *SV = F32(OFF_SV);

    // W8 order: Wq1,Wq2,Wq3,Wk,Wv,Wo1,Wo2,Wo3
    auto W8hi = [&](int i){ return U16(S0 + (size_t)i*1048576); };
    auto W8lo = [&](int i){ return U16(S0 + (size_t)i*1048576 + 524288); };
    auto WChi = [&](int i){ return U16(S1 + (size_t)i*9437184); };
    auto WClo = [&](int i){ return U16(S1 + (size_t)i*9437184 + 4718592); };
    ushort *embChi=U16(S2), *embClo=U16(S2+6291456);
    ushort *embhi=U16(S3), *emblo=U16(S3+6291456);
    ushort *QCthi=U16(S4), *QCtlo=U16(S4+6291456);
    ushort *KCthi=U16(S5), *KCtlo=U16(S5+6291456);
    ushort *VChi=U16(S6), *VClo=U16(S6+6291456);
    float  *ATT = F32(S1);
    ushort *SIMhi=U16(S4), *SIMlo=U16(S4+9437184);
    ushort *KVShi=U16(S2), *KVSlo=U16(S2+6291456);
    float  *Kbf = F32(S6);
    ushort *Kbhi=U16(S1), *Kblo=U16(S1+6291456);
    ushort *Vbhi=U16(S1+12582912), *Vblo=U16(S1+12582912+6291456);
    ushort *VThi=U16(S2), *VTlo=U16(S2+6291456);
    float  *QBf = F32(S6);
    ushort *QBhi=U16(S4), *QBlo=U16(S4+6291456);
    ushort *CTXhi=U16(S5), *CTXlo=U16(S5+6291456);

    dim3 blk(256);
    hipMemsetAsync(d_ws, 0, ZERO_BYTES, stream);

    // fp32 -> bf16 hi/lo conversions
    CvtJobs J;
    J.src[0]=embC;   J.hi[0]=embChi; J.lo[0]=embClo; J.n[0]=2048*KVCH;
    for (int s=0;s<3;++s){ J.src[1+s]=emb[s]; J.hi[1+s]=embhi+(size_t)s*1048576; J.lo[1+s]=emblo+(size_t)s*1048576; J.n[1+s]=2048*EDIM/2*1; }
    J.n[1]=J.n[2]=J.n[3]=2048*EDIM/2*1; // fix below
    for (int s=0;s<3;++s) J.n[1+s] = 2*NTOK*EDIM;      // 1,048,576
    for (int s=0;s<3;++s){ J.src[4+s]=WqF[s]; J.hi[4+s]=W8hi(s); J.lo[4+s]=W8lo(s); J.n[4+s]=EDIM*EDIM; }
    J.src[7]=WkF; J.hi[7]=W8hi(3); J.lo[7]=W8lo(3); J.n[7]=EDIM*EDIM;
    J.src[8]=WvF; J.hi[8]=W8hi(4); J.lo[8]=W8lo(4); J.n[8]=EDIM*EDIM;
    for (int s=0;s<3;++s){ J.src[9+s]=WCF[s]; J.hi[9+s]=WChi(s); J.lo[9+s]=WClo(s); J.n[9+s]=KVCH*KVCH; }
    for (int s=0;s<3;++s){ J.src[12+s]=WoF[s]; J.hi[12+s]=W8hi(5+s); J.lo[12+s]=W8lo(5+s); J.n[12+s]=EDIM*EDIM; }
    cvt_hilo<<<dim3(3072, NCVT), blk, 0, stream>>>(J);

    // channel projections -> QCt/KCt (transposed) and VC (natural)
    mgemm<<<dim3(12,8,2), blk, 0, stream>>>(embChi, embClo, WChi(0), WClo(0),
        nullptr,nullptr,nullptr, QCthi, QCtlo, KVCH, KVCH, KVCH, 0, NTOK,
        1, (long)NTOK*KVCH,0, 0,0, (long)KVCH*NTOK,0);
    mgemm<<<dim3(12,8,2), blk, 0, stream>>>(embChi, embClo, WChi(1), WClo(1),
        nullptr,nullptr,nullptr, KCthi, KCtlo, KVCH, KVCH, KVCH, 0, NTOK,
        1, (long)NTOK*KVCH,0, 0,0, (long)KVCH*NTOK,0);
    mgemm<<<dim3(12,8,2), blk, 0, stream>>>(embChi, embClo, WChi(2), WClo(2),
        nullptr, VChi, VClo, nullptr,nullptr, KVCH, KVCH, KVCH, KVCH, 0,
        1, (long)NTOK*KVCH,0, 0,0, (long)NTOK*KVCH,0);
    // ATT[b] = QC^T KC  (abT on transposed panels)
    mgemm<<<dim3(12,12,2), blk, 0, stream>>>(QCthi, QCtlo, KCthi, KCtlo,
        ATT, nullptr,nullptr,nullptr,nullptr, NTOK, NTOK, NTOK, KVCH, 0,
        1, (long)KVCH*NTOK,0, (long)KVCH*NTOK,0, (long)KVCH*KVCH,0);
    chan_meanvar<<<dim3(2304,2), blk, 0, stream>>>(ATT, CH);
    chan_softmax<<<dim3(1536,2), blk, 0, stream>>>(ATT, CH, SIMhi, SIMlo);
    // KVS[b, j*N+n, e] = sum_d SIM[b, j*E+e, d] * VC[b, n, d]
    mgemm<<<dim3(4,8,6), blk, 0, stream>>>(VChi, VClo, SIMhi, SIMlo,
        nullptr, KVShi, KVSlo, nullptr,nullptr, KVCH, KVCH, KVCH, EDIM, 0,
        3, (long)NTOK*KVCH,0, (long)KVCH*KVCH,(long)EDIM*KVCH, (long)TKV*EDIM,(long)NTOK*EDIM);
    // K/V projections
    mgemm<<<dim3(4,48,1), blk, 0, stream>>>(KVShi, KVSlo, W8hi(3), W8lo(3),
        Kbf, Kbhi, Kblo, nullptr,nullptr, EDIM, EDIM, EDIM, EDIM, 0, 1, 0,0,0,0,0,0);
    mgemm<<<dim3(4,48,1), blk, 0, stream>>>(KVShi, KVSlo, W8hi(4), W8lo(4),
        nullptr, Vbhi, Vblo, nullptr,nullptr, EDIM, EDIM, EDIM, EDIM, 0, 1, 0,0,0,0,0,0);
    vtrans<<<dim3(48,8,2), blk, 0, stream>>>(Vbhi, Vblo, VThi, VTlo);
    gram64<<<dim3(16,8,1), blk, 0, stream>>>(Kbf, TKV, GK, SK, 0,0,0);
    // Q projections (3 streams)
    for (int s=0;s<3;++s)
        mgemm<<<dim3(4,16,1), blk, 0, stream>>>(embhi+(size_t)s*1048576, emblo+(size_t)s*1048576,
            W8hi(s), W8lo(s), QBf+(size_t)s*1048576, QBhi+(size_t)s*1048576, QBlo+(size_t)s*1048576,
            nullptr,nullptr, EDIM, EDIM, EDIM, EDIM, 0, 1, 0,0,0,0,0,0);
    gram64<<<dim3(16,8,3), blk, 0, stream>>>(QBf, NTOK, GQ, SQm, 1048576, 65536, 1024);
    spatial_scale<<<dim3(16,3), blk, 0, stream>>>(GQ, GK, SQm, SK, SV);
    flash_mfma<<<dim3(16,16,3), blk, 0, stream>>>(QBhi, QBlo, Kbhi, Kblo, VThi, VTlo, SV, CTXhi, CTXlo);
    // output projections
    for (int s=0;s<3;++s)
        mgemm<<<dim3(4,16,1), blk, 0, stream>>>(CTXhi+(size_t)s*1048576, CTXlo+(size_t)s*1048576,
            W8hi(5+s), W8lo(5+s), out+(size_t)s*1048576, nullptr,nullptr,nullptr,nullptr,
            EDIM, EDIM, EDIM, EDIM, 0, 1, 0,0,0,0,0,0);
}

// Round 4
// 907.714 us; speedup vs baseline: 2.4264x; 1.9462x over previous
//
#include <hip/hip_runtime.h>
#include <math.h>

#define NTOK 1024
#define EDIM 512
#define KVCH 1536
#define TKV  3072

typedef __bf16 bf16x8 __attribute__((ext_vector_type(8)));
typedef float f32x4 __attribute__((ext_vector_type(4)));
#define MFMA16(a,b,c) __builtin_amdgcn_mfma_f32_16x16x32_bf16(a,b,c,0,0,0)

__device__ __forceinline__ ushort f2bf(float f){
    uint u = __float_as_uint(f);
    u += 0x7FFFu + ((u>>16)&1u);
    return (ushort)(u>>16);
}
__device__ __forceinline__ float bf2f(ushort h){ return __uint_as_float(((uint)h)<<16); }
__device__ __forceinline__ bf16x8 ldsb8(const ushort* p){ return *(const bf16x8*)p; }

// async global->LDS, 16B per lane. g is PER-LANE, l must be WAVE-UNIFORM base.
__device__ __forceinline__ void async16(const ushort* g, ushort* l){
    __builtin_amdgcn_global_load_lds((const __attribute__((address_space(1))) void*)g,
                                     (__attribute__((address_space(3))) void*)l, 16, 0, 0);
}

// ---------------- batched fp32 -> bf16 hi/lo split ----------------
#define NCVT 15
struct CvtJobs { const float* src[NCVT]; ushort* hi[NCVT]; ushort* lo[NCVT]; int n[NCVT]; };

__global__ __launch_bounds__(256) void cvt_hilo(CvtJobs J)
{
    int a = blockIdx.y;
    int i = (blockIdx.x*256 + threadIdx.x)*4;
    if (i >= J.n[a]) return;
    float4 v = *(const float4*)(J.src[a] + i);
    ushort4 h, l;
    h.x=f2bf(v.x); l.x=f2bf(v.x-bf2f(h.x));
    h.y=f2bf(v.y); l.y=f2bf(v.y-bf2f(h.y));
    h.z=f2bf(v.z); l.z=f2bf(v.z-bf2f(h.z));
    h.w=f2bf(v.w); l.w=f2bf(v.w-bf2f(h.w));
    *(ushort4*)(J.hi[a]+i) = h;
    *(ushort4*)(J.lo[a]+i) = l;
}

// ---------------- MFMA GEMM: C = A @ B^T, bf16x3 split, gload_lds staging ----------------
// A:[M,K] hi/lo, B:[N,K] hi/lo. 128x128 tile, BK=32, 4 waves, linear [128][32] LDS per array.
__global__ __launch_bounds__(256) void mgemm(
    const ushort* __restrict__ Ahi, const ushort* __restrict__ Alo,
    const ushort* __restrict__ Bhi, const ushort* __restrict__ Blo,
    float* __restrict__ Cf, ushort* __restrict__ Chi, ushort* __restrict__ Clo,
    ushort* __restrict__ Cthi, ushort* __restrict__ Ctlo,
    int K, int lda, int ldb, int ldc, int ldct,
    int zmod, long sA0, long sA1, long sB0, long sB1, long sC0, long sC1)
{
    __shared__ ushort Ah[4096], Al[4096], Bh[4096], Bl[4096];
    const int tid = threadIdx.x;
    const int z = blockIdx.z, zb = z / zmod, zj = z - zb*zmod;
    const size_t aoff = (size_t)zb*sA0 + (size_t)zj*sA1;
    const size_t boff = (size_t)zb*sB0 + (size_t)zj*sB1;
    const size_t coff = (size_t)zb*sC0 + (size_t)zj*sC1;
    const int m0 = blockIdx.y<<7, n0 = blockIdx.x<<7;
    const int wave = tid>>6, lane = tid&63;
    const int wr = wave>>1, wc = wave&1;
    const int fr = lane&15, fq = lane>>4;
    const int srow = (wave<<5) + (lane>>2);  // staging row (it=0)
    const int scg  = (lane&3)<<3;            // staging col in u16
    f32x4 acc[4][4];
    #pragma unroll
    for (int i=0;i<4;++i)
        #pragma unroll
        for (int j=0;j<4;++j) acc[i][j] = (f32x4){0.f,0.f,0.f,0.f};

    for (int k0=0; k0<K; k0+=32) {
        #pragma unroll
        for (int it=0; it<2; ++it) {
            int row = srow + (it<<4);
            int lb = ((wave<<5) + (it<<4)) << 5;   // uniform base, u16
            size_t ga = aoff + (size_t)(m0+row)*lda + k0 + scg;
            size_t gb = boff + (size_t)(n0+row)*ldb + k0 + scg;
            async16(Ahi+ga, &Ah[lb]);
            async16(Alo+ga, &Al[lb]);
            async16(Bhi+gb, &Bh[lb]);
            async16(Blo+gb, &Bl[lb]);
        }
        __syncthreads();
        bf16x8 fah[4], fal[4];
        #pragma unroll
        for (int m=0;m<4;++m) {
            int o = ((wr*64 + m*16 + fr)<<5) + (fq<<3);
            fah[m] = ldsb8(&Ah[o]); fal[m] = ldsb8(&Al[o]);
        }
        #pragma unroll
        for (int n=0;n<4;++n) {
            int o = ((wc*64 + n*16 + fr)<<5) + (fq<<3);
            bf16x8 fbh = ldsb8(&Bh[o]), fbl = ldsb8(&Bl[o]);
            #pragma unroll
            for (int m=0;m<4;++m) {
                acc[m][n] = MFMA16(fah[m], fbh, acc[m][n]);
                acc[m][n] = MFMA16(fah[m], fbl, acc[m][n]);
                acc[m][n] = MFMA16(fal[m], fbh, acc[m][n]);
            }
        }
        __syncthreads();
    }
    #pragma unroll
    for (int m=0;m<4;++m) {
        #pragma unroll
        for (int n=0;n<4;++n) {
            int row = m0 + wr*64 + m*16 + fq*4;
            int col = n0 + wc*64 + n*16 + fr;
            f32x4 v = acc[m][n];
            if (Cf) {
                #pragma unroll
                for (int r=0;r<4;++r) Cf[coff + (size_t)(row+r)*ldc + col] = v[r];
            }
            if (Chi) {
                #pragma unroll
                for (int r=0;r<4;++r) {
                    ushort hh = f2bf(v[r]);
                    size_t o = coff + (size_t)(row+r)*ldc + col;
                    Chi[o] = hh; Clo[o] = f2bf(v[r]-bf2f(hh));
                }
            }
            if (Cthi) {
                ushort4 h4, l4;
                #pragma unroll
                for (int r=0;r<4;++r) {
                    ushort hh = f2bf(v[r]);
                    ((ushort*)&h4)[r] = hh;
                    ((ushort*)&l4)[r] = f2bf(v[r]-bf2f(hh));
                }
                size_t o = coff + (size_t)col*ldct + row;
                *(ushort4*)(Cthi+o) = h4;
                *(ushort4*)(Ctlo+o) = l4;
            }
        }
    }
}

// ---------------- channel attn mean/var over [KVC,KVC] per batch ----------------
__global__ __launch_bounds__(256) void chan_meanvar(const float* __restrict__ ATT, double* __restrict__ ST)
{
    size_t base = (size_t)blockIdx.y * ((size_t)KVCH * KVCH) + (size_t)blockIdx.x * 1024;
    int tid = threadIdx.x;
    float4 v = *(const float4*)(ATT + base + tid * 4);
    double s  = (double)v.x + (double)v.y + (double)v.z + (double)v.w;
    double s2 = (double)v.x*v.x + (double)v.y*v.y + (double)v.z*v.z + (double)v.w*v.w;
    #pragma unroll
    for (int m = 32; m; m >>= 1) { s += __shfl_xor(s, m); s2 += __shfl_xor(s2, m); }
    __shared__ double ls[4], ls2[4];
    int w = tid >> 6;
    if ((tid & 63) == 0) { ls[w] = s; ls2[w] = s2; }
    __syncthreads();
    if (tid == 0) {
        atomicAdd(&ST[2*blockIdx.y],   ls[0]+ls[1]+ls[2]+ls[3]);
        atomicAdd(&ST[2*blockIdx.y+1], ls2[0]+ls2[1]+ls2[2]+ls2[3]);
    }
}

// ---------------- channel softmax row-wise -> bf16 hi/lo ----------------
__global__ __launch_bounds__(256) void chan_softmax(const float* __restrict__ ATT, const double* __restrict__ ST,
                                                    ushort* __restrict__ Shi, ushort* __restrict__ Slo)
{
    int b = blockIdx.y;
    size_t ro = (size_t)b * KVCH * KVCH + (size_t)blockIdx.x * KVCH;
    const float* p = ATT + ro;
    ushort* ph = Shi + ro;
    ushort* pl = Slo + ro;
    double cnt = (double)KVCH * (double)KVCH;
    double mean = ST[2*b] / cnt;
    double var  = ST[2*b+1] / cnt - mean * mean;
    float sc = (float)(1.0 / sqrt(var + 1e-5));
    int tid = threadIdx.x;
    float x[6];
    #pragma unroll
    for (int k = 0; k < 6; ++k) x[k] = p[tid + (k << 8)] * sc;
    float mx = fmaxf(fmaxf(fmaxf(x[0],x[1]),fmaxf(x[2],x[3])),fmaxf(x[4],x[5]));
    #pragma unroll
    for (int m = 32; m; m >>= 1) mx = fmaxf(mx, __shfl_xor(mx, m));
    __shared__ float red[4];
    int w = tid >> 6;
    if ((tid & 63) == 0) red[w] = mx;
    __syncthreads();
    mx = fmaxf(fmaxf(red[0],red[1]), fmaxf(red[2],red[3]));
    __syncthreads();
    float e[6]; float sum = 0.f;
    #pragma unroll
    for (int k = 0; k < 6; ++k) { e[k] = __expf(x[k] - mx); sum += e[k]; }
    #pragma unroll
    for (int m = 32; m; m >>= 1) sum += __shfl_xor(sum, m);
    if ((tid & 63) == 0) red[w] = sum;
    __syncthreads();
    sum = red[0]+red[1]+red[2]+red[3];
    float inv = 1.0f / sum;
    #pragma unroll
    for (int k = 0; k < 6; ++k) {
        float pv = e[k] * inv;
        ushort hh = f2bf(pv);
        ph[tid + (k << 8)] = hh;
        pl[tid + (k << 8)] = f2bf(pv - bf2f(hh));
    }
}

// ---------------- per (b,h) 64x64 Gram + column sums, bf16 hi/lo input ----------------
__global__ __launch_bounds__(256) void gram64(const ushort* __restrict__ Xhi, const ushort* __restrict__ Xlo,
                                              int T, float* __restrict__ G, float* __restrict__ CS,
                                              long sX, long sG, long sCS)
{
    int zz = blockIdx.z;
    Xhi += (size_t)zz * sX; Xlo += (size_t)zz * sX;
    G += (size_t)zz * sG; CS += (size_t)zz * sCS;
    int bh = blockIdx.x;
    int b = bh >> 3, h = bh & 7;
    const ushort* Xbh = Xhi + (size_t)b * T * EDIM + h * 64;
    const ushort* Xbl = Xlo + (size_t)b * T * EDIM + h * 64;
    int rows = T / gridDim.y;
    int t0 = blockIdx.y * rows;
    __shared__ float Xs[4][64];
    int tid = threadIdx.x;
    int i0 = (tid >> 4) << 2, j0 = (tid & 15) << 2;
    float acc[4][4] = {};
    float cs = 0.f;
    for (int t = t0; t < t0 + rows; t += 4) {
        __syncthreads();
        int r = tid >> 6, c = tid & 63;
        size_t gidx = (size_t)(t + r) * EDIM + c;
        Xs[r][c] = bf2f(Xbh[gidx]) + bf2f(Xbl[gidx]);
        __syncthreads();
        #pragma unroll
        for (int rr = 0; rr < 4; ++rr) {
            float xi0=Xs[rr][i0], xi1=Xs[rr][i0+1], xi2=Xs[rr][i0+2], xi3=Xs[rr][i0+3];
            float xj0=Xs[rr][j0], xj1=Xs[rr][j0+1], xj2=Xs[rr][j0+2], xj3=Xs[rr][j0+3];
            acc[0][0]=fmaf(xi0,xj0,acc[0][0]); acc[0][1]=fmaf(xi0,xj1,acc[0][1]); acc[0][2]=fmaf(xi0,xj2,acc[0][2]); acc[0][3]=fmaf(xi0,xj3,acc[0][3]);
            acc[1][0]=fmaf(xi1,xj0,acc[1][0]); acc[1][1]=fmaf(xi1,xj1,acc[1][1]); acc[1][2]=fmaf(xi1,xj2,acc[1][2]); acc[1][3]=fmaf(xi1,xj3,acc[1][3]);
            acc[2][0]=fmaf(xi2,xj0,acc[2][0]); acc[2][1]=fmaf(xi2,xj1,acc[2][1]); acc[2][2]=fmaf(xi2,xj2,acc[2][2]); acc[2][3]=fmaf(xi2,xj3,acc[2][3]);
            acc[3][0]=fmaf(xi3,xj0,acc[3][0]); acc[3][1]=fmaf(xi3,xj1,acc[3][1]); acc[3][2]=fmaf(xi3,xj2,acc[3][2]); acc[3][3]=fmaf(xi3,xj3,acc[3][3]);
        }
        if (tid < 64) cs += Xs[0][tid] + Xs[1][tid] + Xs[2][tid] + Xs[3][tid];
    }
    float* Gp = G + (size_t)bh * 4096;
    #pragma unroll
    for (int i = 0; i < 4; ++i)
        #pragma unroll
        for (int j = 0; j < 4; ++j)
            atomicAdd(&Gp[(i0 + i) * 64 + j0 + j], acc[i][j]);
    if (tid < 64) atomicAdd(&CS[bh * 64 + tid], cs);
}

// ---------------- per (st,b,h) scale = rsqrt(var(QK^T)+eps) ----------------
__global__ __launch_bounds__(256) void spatial_scale(
    const float* __restrict__ GQ, const float* __restrict__ GK,
    const float* __restrict__ SQm, const float* __restrict__ SKm, float* __restrict__ SVo)
{
    int st = blockIdx.y, bh = blockIdx.x, tid = threadIdx.x;
    const float* gq = GQ + (size_t)st*65536 + bh*4096;
    const float* gk = GK + bh*4096;
    double e2 = 0.0;
    for (int i = tid; i < 4096; i += 256)
        e2 += (double)gq[i] * (double)gk[i];
    double mm = 0.0;
    if (tid < 64) mm = (double)SQm[(size_t)st*1024 + bh*64 + tid] * (double)SKm[bh*64 + tid];
    #pragma unroll
    for (int m = 32; m; m >>= 1) { e2 += __shfl_xor(e2, m); mm += __shfl_xor(mm, m); }
    __shared__ double se[4], sm[4];
    int w = tid >> 6;
    if ((tid & 63) == 0) { se[w] = e2; sm[w] = mm; }
    __syncthreads();
    if (tid == 0) {
        double cnt = (double)NTOK * (double)TKV;
        double E2 = (se[0]+se[1]+se[2]+se[3]) / cnt;
        double M  = (sm[0]+sm[1]+sm[2]+sm[3]) / cnt;
        double var = E2 - M * M;
        SVo[st*16+bh] = (float)(1.0 / sqrt(var + 1e-5));
    }
}

// ---------------- V transpose per head: [B,TKV,E] -> [B,H,64,TKV] (bf16 hi/lo) ----------------
__global__ __launch_bounds__(256) void vtrans(const ushort* __restrict__ Vhi, const ushort* __restrict__ Vlo,
                                              ushort* __restrict__ Thi, ushort* __restrict__ Tlo)
{
    __shared__ ushort th[64*72], tl[64*72];
    int t0 = blockIdx.x<<6, h = blockIdx.y, b = blockIdx.z;
    int tid = threadIdx.x;
    #pragma unroll
    for (int it=0; it<2; ++it) {
        int idx = (it<<8)+tid, row = idx>>3, seg = (idx&7)<<3;
        size_t g = (size_t)(b*TKV + t0 + row)*EDIM + h*64 + seg;
        *(uint4*)&th[row*72+seg] = *(const uint4*)(Vhi+g);
        *(uint4*)&tl[row*72+seg] = *(const uint4*)(Vlo+g);
    }
    __syncthreads();
    #pragma unroll
    for (int it=0; it<2; ++it) {
        int idx = (it<<8)+tid, d = idx>>3, ts = (idx&7)<<3;
        ushort oh[8], ol[8];
        #pragma unroll
        for (int j=0;j<8;++j) { oh[j] = th[(ts+j)*72 + d]; ol[j] = tl[(ts+j)*72 + d]; }
        size_t g = ((size_t)(b*8+h)*64 + d)*TKV + t0 + ts;
        *(uint4*)(Thi+g) = *(uint4*)oh;
        *(uint4*)(Tlo+g) = *(uint4*)ol;
    }
}

// ---------------- MFMA flash attention (bf16x3), Q in regs, swizzled K/V/P LDS ----------------
__global__ __launch_bounds__(256) void flash_mfma(
    const ushort* __restrict__ Qhi, const ushort* __restrict__ Qlo,
    const ushort* __restrict__ Khi, const ushort* __restrict__ Klo,
    const ushort* __restrict__ VThi, const ushort* __restrict__ VTlo,
    const float* __restrict__ SV,
    ushort* __restrict__ Ohi, ushort* __restrict__ Olo)
{
    __shared__ ushort Kh[4096], Kl[4096], Vh[4096], Vl[4096], Ph[4096], Pl[4096];
    const int st = blockIdx.z, bh = blockIdx.y, b = bh>>3, h = bh&7;
    const int n0 = blockIdx.x<<6;
    const int tid = threadIdx.x, wave = tid>>6, lane = tid&63;
    const int fr = lane&15, fq = lane>>4;
    const float sc = SV[st*16 + bh];
    const size_t qb = (size_t)st*(2048*512) + (size_t)(b*1024 + n0)*512 + h*64;
    // Q fragments in registers (A operand: row=fr, k=ks*32+fq*8)
    bf16x8 qfh[2], qfl[2];
    {
        const ushort* qph = Qhi + qb + (size_t)(wave*16 + fr)*512;
        const ushort* qpl = Qlo + qb + (size_t)(wave*16 + fr)*512;
        #pragma unroll
        for (int ks=0; ks<2; ++ks) {
            qfh[ks] = ldsb8(qph + ks*32 + fq*8);
            qfl[ks] = ldsb8(qpl + ks*32 + fq*8);
        }
    }
    f32x4 accO[4]; float mr[4], lr[4];
    #pragma unroll
    for (int i=0;i<4;++i){ accO[i]=(f32x4){0.f,0.f,0.f,0.f}; mr[i]=-1e30f; lr[i]=0.f; }
    const size_t kb = (size_t)(b*TKV)*512 + h*64;
    const size_t vbs = ((size_t)(b*8+h)*64)*TKV;
    for (int t0=0; t0<TKV; t0+=64) {
        // staged via gload_lds: linear dest + inverse-swizzled SOURCE (rule #21)
        #pragma unroll
        for (int it=0; it<2; ++it) {
            int r  = (wave<<4) + (it<<3) + (lane>>3);
            int lb = ((wave<<4) + (it<<3)) << 6;          // uniform base, u16
            int gck = ((lane&7) ^ (r&7)) << 3;            // pre-swizzled granule
            size_t gk = kb + (size_t)(t0+r)*512 + gck;
            size_t gv = vbs + (size_t)r*TKV + t0 + gck;
            async16(Khi+gk, &Kh[lb]);
            async16(Klo+gk, &Kl[lb]);
            async16(VThi+gv, &Vh[lb]);
            async16(VTlo+gv, &Vl[lb]);
        }
        __syncthreads();
        f32x4 s[4];
        #pragma unroll
        for (int i=0;i<4;++i) s[i]=(f32x4){0.f,0.f,0.f,0.f};
        #pragma unroll
        for (int ks=0; ks<2; ++ks) {
            #pragma unroll
            for (int nf=0; nf<4; ++nf) {
                int r = nf*16+fr;
                int ko = (r<<6) + ((ks*32 + fq*8) ^ ((r&7)<<3));
                bf16x8 kh = ldsb8(&Kh[ko]), kl = ldsb8(&Kl[ko]);
                s[nf] = MFMA16(qfh[ks], kh, s[nf]);
                s[nf] = MFMA16(qfh[ks], kl, s[nf]);
                s[nf] = MFMA16(qfl[ks], kh, s[nf]);
            }
        }
        #pragma unroll
        for (int reg=0; reg<4; ++reg) {
            float p[4];
            float tm = fmaxf(fmaxf(s[0][reg],s[1][reg]), fmaxf(s[2][reg],s[3][reg]));
            tm = fmaxf(tm, __shfl_xor(tm,1,16));
            tm = fmaxf(tm, __shfl_xor(tm,2,16));
            tm = fmaxf(tm, __shfl_xor(tm,4,16));
            tm = fmaxf(tm, __shfl_xor(tm,8,16));
            float mn = fmaxf(mr[reg], sc*tm);
            float al = __expf(mr[reg]-mn);
            mr[reg] = mn;
            float ps = 0.f;
            #pragma unroll
            for (int nf=0;nf<4;++nf){ p[nf] = __expf(fmaf(sc, s[nf][reg], -mn)); ps += p[nf]; }
            ps += __shfl_xor(ps,1,16); ps += __shfl_xor(ps,2,16);
            ps += __shfl_xor(ps,4,16); ps += __shfl_xor(ps,8,16);
            lr[reg] = lr[reg]*al + ps;
            #pragma unroll
            for (int df=0;df<4;++df) accO[df][reg] *= al;
            int prow = fq*4+reg;
            #pragma unroll
            for (int nf=0;nf<4;++nf) {
                ushort hh = f2bf(p[nf]);
                int pidx = (wave<<10) + (prow<<6) + ((nf*16+fr) ^ ((prow&7)<<3));
                Ph[pidx] = hh;
                Pl[pidx] = f2bf(p[nf]-bf2f(hh));
            }
        }
        #pragma unroll
        for (int ks=0; ks<2; ++ks) {
            int po = (wave<<10) + (fr<<6) + ((ks*32 + fq*8) ^ ((fr&7)<<3));
            bf16x8 ph = ldsb8(&Ph[po]), pl = ldsb8(&Pl[po]);
            #pragma unroll
            for (int df=0; df<4; ++df) {
                int d = df*16+fr;
                int vo = (d<<6) + ((ks*32 + fq*8) ^ ((d&7)<<3));
                bf16x8 vh = ldsb8(&Vh[vo]), vl = ldsb8(&Vl[vo]);
                accO[df] = MFMA16(ph, vh, accO[df]);
                accO[df] = MFMA16(ph, vl, accO[df]);
                accO[df] = MFMA16(pl, vh, accO[df]);
            }
        }
        __syncthreads();
    }
    #pragma unroll
    for (int reg=0; reg<4; ++reg) {
        float inv = 1.f/lr[reg];
        int row = n0 + wave*16 + fq*4 + reg;
        #pragma unroll
        for (int df=0; df<4; ++df) {
            float v = accO[df][reg]*inv;
            size_t o = (size_t)st*(2048*512) + (size_t)(b*1024+row)*512 + h*64 + df*16 + fr;
            ushort hh = f2bf(v);
            Ohi[o] = hh; Olo[o] = f2bf(v-bf2f(hh));
        }
    }
}

// ---------------- workspace layout (byte offsets) ----------------
constexpr size_t OFF_CH  = 0;           // 8 doubles
constexpr size_t OFF_GK  = 64;          // 65536 f32
constexpr size_t OFF_SK  = 262208;      // 1024 f32
constexpr size_t OFF_GQ  = 266304;      // 3*65536 f32
constexpr size_t OFF_SQM = 1052736;     // 3*1024 f32
constexpr size_t OFF_SV  = 1065024;     // 48 f32
constexpr size_t ZERO_BYTES = 1065024;
constexpr size_t S0 = 1065472;          // W8: 8 x 1 MB (hi 512KB + lo 512KB)
constexpr size_t S1 = S0 + 8388608;     // WC: 3 x 9437184; overlays: ATT f32; Kb hilo; Vb hilo
constexpr size_t S2 = S1 + 28311552;    // embC hilo; overlays: KVS hilo; VT hilo
constexpr size_t S3 = S2 + 12582912;    // emb123 hilo
constexpr size_t S4 = S3 + 12582912;    // QCt hilo; overlays: SIMhi(+into S5); QB hilo
constexpr size_t S5 = S4 + 12582912;    // KCt hilo; overlays: SIMlo tail; CTX hilo
constexpr size_t S6 = S5 + 12582912;    // VC hilo
// total = S6 + 12582912 = 100,680,192 bytes (~96 MB)

extern "C" void kernel_launch(void* const* d_in, const int* in_sizes, int n_in,
                              void* d_out, int out_size, void* d_ws, size_t ws_size,
                              hipStream_t stream)
{
    const float* emb[3] = {(const float*)d_in[0], (const float*)d_in[1], (const float*)d_in[2]};
    const float* embC = (const float*)d_in[3];
    const float* WqF[3] = {(const float*)d_in[4], (const float*)d_in[5], (const float*)d_in[6]};
    const float* WkF  = (const float*)d_in[7];
    const float* WvF  = (const float*)d_in[8];
    const float* WCF[3] = {(const float*)d_in[9], (const float*)d_in[10], (const float*)d_in[11]};
    const float* WoF[3] = {(const float*)d_in[12], (const float*)d_in[13], (const float*)d_in[14]};
    float* out = (float*)d_out;
    char* ws = (char*)d_ws;

    auto U16 = [&](size_t off)->ushort* { return (ushort*)(ws + off); };
    auto F32 = [&](size_t off)->float*  { return (float*)(ws + off); };

    double* CH = (double*)(ws + OFF_CH);
    float *GK = F32(OFF_GK), *SK = F32(OFF_SK), *GQ = F32(OFF_GQ), *SQm = F32(OFF_SQM), *SV = F32(OFF_SV);

    // W8 order: Wq1,Wq2,Wq3,Wk,Wv,Wo1,Wo2,Wo3
    auto W8hi = [&](int i){ return U16(S0 + (size_t)i*1048576); };
    auto W8lo = [&](int i){ return U16(S0 + (size_t)i*1048576 + 524288); };
    auto WChi = [&](int i){ return U16(S1 + (size_t)i*9437184); };
    auto WClo = [&](int i){ return U16(S1 + (size_t)i*9437184 + 4718592); };
    ushort *embChi=U16(S2), *embClo=U16(S2+6291456);
    ushort *embhi=U16(S3), *emblo=U16(S3+6291456);
    ushort *QCthi=U16(S4), *QCtlo=U16(S4+6291456);
    ushort *KCthi=U16(S5), *KCtlo=U16(S5+6291456);
    ushort *VChi=U16(S6), *VClo=U16(S6+6291456);
    float  *ATT = F32(S1);
    ushort *SIMhi=U16(S4), *SIMlo=U16(S4+9437184);
    ushort *KVShi=U16(S2), *KVSlo=U16(S2+6291456);
    ushort *Kbhi=U16(S1), *Kblo=U16(S1+6291456);
    ushort *Vbhi=U16(S1+12582912), *Vblo=U16(S1+12582912+6291456);
    ushort *VThi=U16(S2), *VTlo=U16(S2+6291456);
    ushort *QBhi=U16(S4), *QBlo=U16(S4+6291456);
    ushort *CTXhi=U16(S5), *CTXlo=U16(S5+6291456);

    dim3 blk(256);
    hipMemsetAsync(d_ws, 0, ZERO_BYTES, stream);

    // fp32 -> bf16 hi/lo conversions
    CvtJobs J;
    J.src[0]=embC;   J.hi[0]=embChi; J.lo[0]=embClo; J.n[0]=2048*KVCH;
    for (int s=0;s<3;++s){ J.src[1+s]=emb[s]; J.hi[1+s]=embhi+(size_t)s*1048576; J.lo[1+s]=emblo+(size_t)s*1048576; J.n[1+s]=2*NTOK*EDIM; }
    for (int s=0;s<3;++s){ J.src[4+s]=WqF[s]; J.hi[4+s]=W8hi(s); J.lo[4+s]=W8lo(s); J.n[4+s]=EDIM*EDIM; }
    J.src[7]=WkF; J.hi[7]=W8hi(3); J.lo[7]=W8lo(3); J.n[7]=EDIM*EDIM;
    J.src[8]=WvF; J.hi[8]=W8hi(4); J.lo[8]=W8lo(4); J.n[8]=EDIM*EDIM;
    for (int s=0;s<3;++s){ J.src[9+s]=WCF[s]; J.hi[9+s]=WChi(s); J.lo[9+s]=WClo(s); J.n[9+s]=KVCH*KVCH; }
    for (int s=0;s<3;++s){ J.src[12+s]=WoF[s]; J.hi[12+s]=W8hi(5+s); J.lo[12+s]=W8lo(5+s); J.n[12+s]=EDIM*EDIM; }
    cvt_hilo<<<dim3(3072, NCVT), blk, 0, stream>>>(J);

    // channel Q/K projections merged: z = w*2 + b  (w: WqC/WkC), transposed outputs
    mgemm<<<dim3(12,8,4), blk, 0, stream>>>(embChi, embClo, WChi(0), WClo(0),
        nullptr,nullptr,nullptr, QCthi, QCtlo, KVCH, KVCH, KVCH, 0, NTOK,
        2, 0,(long)NTOK*KVCH, 4718592,0, 6291456,(long)KVCH*NTOK);
    // channel V projection (natural layout)
    mgemm<<<dim3(12,8,2), blk, 0, stream>>>(embChi, embClo, WChi(2), WClo(2),
        nullptr, VChi, VClo, nullptr,nullptr, KVCH, KVCH, KVCH, KVCH, 0,
        1, (long)NTOK*KVCH,0, 0,0, (long)NTOK*KVCH,0);
    // ATT[b] = QC^T KC
    mgemm<<<dim3(12,12,2), blk, 0, stream>>>(QCthi, QCtlo, KCthi, KCtlo,
        ATT, nullptr,nullptr,nullptr,nullptr, NTOK, NTOK, NTOK, KVCH, 0,
        1, (long)KVCH*NTOK,0, (long)KVCH*NTOK,0, (long)KVCH*KVCH,0);
    chan_meanvar<<<dim3(2304,2), blk, 0, stream>>>(ATT, CH);
    chan_softmax<<<dim3(1536,2), blk, 0, stream>>>(ATT, CH, SIMhi, SIMlo);
    // KVS[b, j*N+n, e] = sum_d SIM[b, j*E+e, d] * VC[b, n, d]
    mgemm<<<dim3(4,8,6), blk, 0, stream>>>(VChi, VClo, SIMhi, SIMlo,
        nullptr, KVShi, KVSlo, nullptr,nullptr, KVCH, KVCH, KVCH, EDIM, 0,
        3, (long)NTOK*KVCH,0, (long)KVCH*KVCH,(long)EDIM*KVCH, (long)TKV*EDIM,(long)NTOK*EDIM);
    // K/V projections merged: z = w (Wk/Wv)
    mgemm<<<dim3(4,48,2), blk, 0, stream>>>(KVShi, KVSlo, W8hi(3), W8lo(3),
        nullptr, Kbhi, Kblo, nullptr,nullptr, EDIM, EDIM, EDIM, EDIM, 0,
        1, 0,0, 524288,0, 6291456,0);
    vtrans<<<dim3(48,8,2), blk, 0, stream>>>(Vbhi, Vblo, VThi, VTlo);
    gram64<<<dim3(16,8,1), blk, 0, stream>>>(Kbhi, Kblo, TKV, GK, SK, 0,0,0);
    // Q projections merged: z = stream
    mgemm<<<dim3(4,16,3), blk, 0, stream>>>(embhi, emblo, W8hi(0), W8lo(0),
        nullptr, QBhi, QBlo, nullptr,nullptr, EDIM, EDIM, EDIM, EDIM, 0,
        1, 1048576,0, 524288,0, 1048576,0);
    gram64<<<dim3(16,8,3), blk, 0, stream>>>(QBhi, QBlo, NTOK, GQ, SQm, 1048576, 65536, 1024);
    spatial_scale<<<dim3(16,3), blk, 0, stream>>>(GQ, GK, SQm, SK, SV);
    flash_mfma<<<dim3(16,16,3), blk, 0, stream>>>(QBhi, QBlo, Kbhi, Kblo, VThi, VTlo, SV, CTXhi, CTXlo);
    // output projections merged: z = stream
    mgemm<<<dim3(4,16,3), blk, 0, stream>>>(CTXhi, CTXlo, W8hi(5), W8lo(5),
        out, nullptr,nullptr,nullptr,nullptr, EDIM, EDIM, EDIM, EDIM, 0,
        1, 1048576,0, 524288,0, 1048576,0);
}

// Round 6
// 656.596 us; speedup vs baseline: 3.3544x; 1.3825x over previous
//
#include <hip/hip_runtime.h>
#include <math.h>

#define NTOK 1024
#define EDIM 512
#define KVCH 1536
#define TKV  3072
#define VSTRIDE 6144

typedef __bf16 bf16x8 __attribute__((ext_vector_type(8)));
typedef float f32x4 __attribute__((ext_vector_type(4)));
#define MFMA16(a,b,c) __builtin_amdgcn_mfma_f32_16x16x32_bf16(a,b,c,0,0,0)

__device__ __forceinline__ ushort f2bf(float f){
    uint u = __float_as_uint(f);
    u += 0x7FFFu + ((u>>16)&1u);
    return (ushort)(u>>16);
}
__device__ __forceinline__ float bf2f(ushort h){ return __uint_as_float(((uint)h)<<16); }
__device__ __forceinline__ bf16x8 ldsb8(const ushort* p){ return *(const bf16x8*)p; }

// async global->LDS, 16B per lane. g is PER-LANE, l must be WAVE-UNIFORM base.
__device__ __forceinline__ void async16(const ushort* g, ushort* l){
    __builtin_amdgcn_global_load_lds((const __attribute__((address_space(1))) void*)g,
                                     (__attribute__((address_space(3))) void*)l, 16, 0, 0);
}

// ---------------- batched fp32 -> bf16 hi/lo split ----------------
#define NCVT 15
struct CvtJobs { const float* src[NCVT]; ushort* hi[NCVT]; ushort* lo[NCVT]; int n[NCVT]; };

__global__ __launch_bounds__(256) void cvt_hilo(CvtJobs J)
{
    int a = blockIdx.y;
    int i = (blockIdx.x*256 + threadIdx.x)*4;
    if (i >= J.n[a]) return;
    float4 v = *(const float4*)(J.src[a] + i);
    ushort4 h, l;
    h.x=f2bf(v.x); l.x=f2bf(v.x-bf2f(h.x));
    h.y=f2bf(v.y); l.y=f2bf(v.y-bf2f(h.y));
    h.z=f2bf(v.z); l.z=f2bf(v.z-bf2f(h.z));
    h.w=f2bf(v.w); l.w=f2bf(v.w-bf2f(h.w));
    *(ushort4*)(J.hi[a]+i) = h;
    *(ushort4*)(J.lo[a]+i) = l;
}

// ---------------- dual-descriptor MFMA GEMM: C = A @ B^T, bf16x3 split ----------------
struct GemmDesc {
    const ushort *Ahi, *Alo, *Bhi, *Blo;
    float* Cf; ushort *Chi, *Clo, *Cthi, *Ctlo;
    double* stats;                     // if set: atomicAdd {sum,sumsq} at stats[2*zb]
    int K, lda, ldb, ldc, ldct;
    int zmod;
    long sA0, sA1, sB0, sB1, sC0, sC1;
};

__global__ __launch_bounds__(256) void mgemmF(GemmDesc D0, GemmDesc D1,
                                              int nblk0, int nx0, int ny0, int nx1, int ny1)
{
    __shared__ ushort Ah[4096], Al[4096], Bh[4096], Bl[4096];
    __shared__ double sred[8];
    const int tid = threadIdx.x;
    int bid = blockIdx.x;
    GemmDesc d; int nx, ny, rel;
    if (bid < nblk0) { d = D0; rel = bid; nx = nx0; ny = ny0; }
    else             { d = D1; rel = bid - nblk0; nx = nx1; ny = ny1; }
    const int bx = rel % nx; int tt = rel / nx;
    const int by = tt % ny;  const int z = tt / ny;
    const int zb = z / d.zmod, zj = z - zb*d.zmod;
    const size_t aoff = (size_t)zb*d.sA0 + (size_t)zj*d.sA1;
    const size_t boff = (size_t)zb*d.sB0 + (size_t)zj*d.sB1;
    const size_t coff = (size_t)zb*d.sC0 + (size_t)zj*d.sC1;
    const int mb = by<<7, nb = bx<<7;
    const int wave = tid>>6, lane = tid&63;
    const int wr = wave>>1, wc = wave&1;
    const int fr = lane&15, fq = lane>>4;
    const int srow = (wave<<5) + (lane>>2);
    const int scg  = (lane&3)<<3;
    f32x4 acc[4][4];
    #pragma unroll
    for (int i=0;i<4;++i)
        #pragma unroll
        for (int j=0;j<4;++j) acc[i][j] = (f32x4){0.f,0.f,0.f,0.f};

    for (int k0=0; k0<d.K; k0+=32) {
        #pragma unroll
        for (int it=0; it<2; ++it) {
            int row = srow + (it<<4);
            int lb = ((wave<<5) + (it<<4)) << 5;
            size_t ga = aoff + (size_t)(mb+row)*d.lda + k0 + scg;
            size_t gb = boff + (size_t)(nb+row)*d.ldb + k0 + scg;
            async16(d.Ahi+ga, &Ah[lb]);
            async16(d.Alo+ga, &Al[lb]);
            async16(d.Bhi+gb, &Bh[lb]);
            async16(d.Blo+gb, &Bl[lb]);
        }
        __syncthreads();
        bf16x8 fah[4], fal[4];
        #pragma unroll
        for (int m=0;m<4;++m) {
            int o = ((wr*64 + m*16 + fr)<<5) + (fq<<3);
            fah[m] = ldsb8(&Ah[o]); fal[m] = ldsb8(&Al[o]);
        }
        #pragma unroll
        for (int n=0;n<4;++n) {
            int o = ((wc*64 + n*16 + fr)<<5) + (fq<<3);
            bf16x8 fbh = ldsb8(&Bh[o]), fbl = ldsb8(&Bl[o]);
            #pragma unroll
            for (int m=0;m<4;++m) {
                acc[m][n] = MFMA16(fah[m], fbh, acc[m][n]);
                acc[m][n] = MFMA16(fah[m], fbl, acc[m][n]);
                acc[m][n] = MFMA16(fal[m], fbh, acc[m][n]);
            }
        }
        __syncthreads();
    }
    #pragma unroll
    for (int m=0;m<4;++m) {
        #pragma unroll
        for (int n=0;n<4;++n) {
            int row = mb + wr*64 + m*16 + fq*4;
            int col = nb + wc*64 + n*16 + fr;
            f32x4 v = acc[m][n];
            if (d.Cf) {
                #pragma unroll
                for (int r=0;r<4;++r) d.Cf[coff + (size_t)(row+r)*d.ldc + col] = v[r];
            }
            if (d.Chi) {
                #pragma unroll
                for (int r=0;r<4;++r) {
                    ushort hh = f2bf(v[r]);
                    size_t o = coff + (size_t)(row+r)*d.ldc + col;
                    d.Chi[o] = hh; d.Clo[o] = f2bf(v[r]-bf2f(hh));
                }
            }
            if (d.Cthi) {
                ushort4 h4, l4;
                #pragma unroll
                for (int r=0;r<4;++r) {
                    ushort hh = f2bf(v[r]);
                    ((ushort*)&h4)[r] = hh;
                    ((ushort*)&l4)[r] = f2bf(v[r]-bf2f(hh));
                }
                size_t o = coff + (size_t)col*d.ldct + row;
                *(ushort4*)(d.Cthi+o) = h4;
                *(ushort4*)(d.Ctlo+o) = l4;
            }
        }
    }
    if (d.stats) {
        double s=0.0, s2=0.0;
        #pragma unroll
        for (int m=0;m<4;++m)
            #pragma unroll
            for (int n=0;n<4;++n)
                #pragma unroll
                for (int r=0;r<4;++r) { double v = acc[m][n][r]; s += v; s2 += v*v; }
        #pragma unroll
        for (int off=32; off; off>>=1) { s += __shfl_xor(s, off); s2 += __shfl_xor(s2, off); }
        if (lane==0){ sred[wave]=s; sred[4+wave]=s2; }
        __syncthreads();
        if (tid==0) {
            atomicAdd(&d.stats[2*zb],   sred[0]+sred[1]+sred[2]+sred[3]);
            atomicAdd(&d.stats[2*zb+1], sred[4]+sred[5]+sred[6]+sred[7]);
        }
    }
}

// ---------------- channel softmax row-wise -> bf16 hi/lo ----------------
__global__ __launch_bounds__(256) void chan_softmax(const float* __restrict__ ATT, const double* __restrict__ ST,
                                                    ushort* __restrict__ Shi, ushort* __restrict__ Slo)
{
    int b = blockIdx.y;
    size_t ro = (size_t)b * KVCH * KVCH + (size_t)blockIdx.x * KVCH;
    const float* p = ATT + ro;
    ushort* ph = Shi + ro;
    ushort* pl = Slo + ro;
    double cnt = (double)KVCH * (double)KVCH;
    double mean = ST[2*b] / cnt;
    double var  = ST[2*b+1] / cnt - mean * mean;
    float sc = (float)(1.0 / sqrt(var + 1e-5));
    int tid = threadIdx.x;
    float x[6];
    #pragma unroll
    for (int k = 0; k < 6; ++k) x[k] = p[tid + (k << 8)] * sc;
    float mx = fmaxf(fmaxf(fmaxf(x[0],x[1]),fmaxf(x[2],x[3])),fmaxf(x[4],x[5]));
    #pragma unroll
    for (int m = 32; m; m >>= 1) mx = fmaxf(mx, __shfl_xor(mx, m));
    __shared__ float red[4];
    int w = tid >> 6;
    if ((tid & 63) == 0) red[w] = mx;
    __syncthreads();
    mx = fmaxf(fmaxf(red[0],red[1]), fmaxf(red[2],red[3]));
    __syncthreads();
    float e[6]; float sum = 0.f;
    #pragma unroll
    for (int k = 0; k < 6; ++k) { e[k] = __expf(x[k] - mx); sum += e[k]; }
    #pragma unroll
    for (int m = 32; m; m >>= 1) sum += __shfl_xor(sum, m);
    if ((tid & 63) == 0) red[w] = sum;
    __syncthreads();
    sum = red[0]+red[1]+red[2]+red[3];
    float inv = 1.0f / sum;
    #pragma unroll
    for (int k = 0; k < 6; ++k) {
        float pv = e[k] * inv;
        ushort hh = f2bf(pv);
        ph[tid + (k << 8)] = hh;
        pl[tid + (k << 8)] = f2bf(pv - bf2f(hh));
    }
}

// ---------------- merged per (b,h) 64x64 Gram + column sums (z=0: K, z=1..3: Q streams) ----------------
__global__ __launch_bounds__(256) void gram4(
    const ushort* __restrict__ Kbhi, const ushort* __restrict__ Kblo,
    const ushort* __restrict__ QBhi, const ushort* __restrict__ QBlo,
    float* __restrict__ GK, float* __restrict__ SK,
    float* __restrict__ GQ, float* __restrict__ SQm)
{
    int z = blockIdx.z;
    const ushort *Xh, *Xl; int T; float *G, *CS;
    if (z == 0) { Xh=Kbhi; Xl=Kblo; T=TKV; G=GK; CS=SK; }
    else { Xh=QBhi+(size_t)(z-1)*1048576; Xl=QBlo+(size_t)(z-1)*1048576;
           T=NTOK; G=GQ+(size_t)(z-1)*65536; CS=SQm+(size_t)(z-1)*1024; }
    int bh = blockIdx.x;
    int b = bh >> 3, h = bh & 7;
    const ushort* Xbh = Xh + (size_t)b * T * EDIM + h * 64;
    const ushort* Xbl = Xl + (size_t)b * T * EDIM + h * 64;
    int rows = T / gridDim.y;
    int t0 = blockIdx.y * rows;
    __shared__ float Xs[4][64];
    int tid = threadIdx.x;
    int i0 = (tid >> 4) << 2, j0 = (tid & 15) << 2;
    float acc[4][4] = {};
    float cs = 0.f;
    for (int t = t0; t < t0 + rows; t += 4) {
        __syncthreads();
        int r = tid >> 6, c = tid & 63;
        size_t gidx = (size_t)(t + r) * EDIM + c;
        Xs[r][c] = bf2f(Xbh[gidx]) + bf2f(Xbl[gidx]);
        __syncthreads();
        #pragma unroll
        for (int rr = 0; rr < 4; ++rr) {
            float xi0=Xs[rr][i0], xi1=Xs[rr][i0+1], xi2=Xs[rr][i0+2], xi3=Xs[rr][i0+3];
            float xj0=Xs[rr][j0], xj1=Xs[rr][j0+1], xj2=Xs[rr][j0+2], xj3=Xs[rr][j0+3];
            acc[0][0]=fmaf(xi0,xj0,acc[0][0]); acc[0][1]=fmaf(xi0,xj1,acc[0][1]); acc[0][2]=fmaf(xi0,xj2,acc[0][2]); acc[0][3]=fmaf(xi0,xj3,acc[0][3]);
            acc[1][0]=fmaf(xi1,xj0,acc[1][0]); acc[1][1]=fmaf(xi1,xj1,acc[1][1]); acc[1][2]=fmaf(xi1,xj2,acc[1][2]); acc[1][3]=fmaf(xi1,xj3,acc[1][3]);
            acc[2][0]=fmaf(xi2,xj0,acc[2][0]); acc[2][1]=fmaf(xi2,xj1,acc[2][1]); acc[2][2]=fmaf(xi2,xj2,acc[2][2]); acc[2][3]=fmaf(xi2,xj3,acc[2][3]);
            acc[3][0]=fmaf(xi3,xj0,acc[3][0]); acc[3][1]=fmaf(xi3,xj1,acc[3][1]); acc[3][2]=fmaf(xi3,xj2,acc[3][2]); acc[3][3]=fmaf(xi3,xj3,acc[3][3]);
        }
        if (tid < 64) cs += Xs[0][tid] + Xs[1][tid] + Xs[2][tid] + Xs[3][tid];
    }
    float* Gp = G + (size_t)bh * 4096;
    #pragma unroll
    for (int i = 0; i < 4; ++i)
        #pragma unroll
        for (int j = 0; j < 4; ++j)
            atomicAdd(&Gp[(i0 + i) * 64 + j0 + j], acc[i][j]);
    if (tid < 64) atomicAdd(&CS[bh * 64 + tid], cs);
}

// ---------------- per (st,b,h) scale = rsqrt(var(QK^T)+eps) ----------------
__global__ __launch_bounds__(256) void spatial_scale(
    const float* __restrict__ GQ, const float* __restrict__ GK,
    const float* __restrict__ SQm, const float* __restrict__ SKm, float* __restrict__ SVo)
{
    int st = blockIdx.y, bh = blockIdx.x, tid = threadIdx.x;
    const float* gq = GQ + (size_t)st*65536 + bh*4096;
    const float* gk = GK + bh*4096;
    double e2 = 0.0;
    for (int i = tid; i < 4096; i += 256)
        e2 += (double)gq[i] * (double)gk[i];
    double mm = 0.0;
    if (tid < 64) mm = (double)SQm[(size_t)st*1024 + bh*64 + tid] * (double)SKm[bh*64 + tid];
    #pragma unroll
    for (int m = 32; m; m >>= 1) { e2 += __shfl_xor(e2, m); mm += __shfl_xor(mm, m); }
    __shared__ double se[4], sm[4];
    int w = tid >> 6;
    if ((tid & 63) == 0) { se[w] = e2; sm[w] = mm; }
    __syncthreads();
    if (tid == 0) {
        double cnt = (double)NTOK * (double)TKV;
        double E2 = (se[0]+se[1]+se[2]+se[3]) / cnt;
        double M  = (sm[0]+sm[1]+sm[2]+sm[3]) / cnt;
        double var = E2 - M * M;
        SVo[st*16+bh] = (float)(1.0 / sqrt(var + 1e-5));
    }
}

// ---------------- MFMA flash attention: no-max softmax (instance-normed logits), bf16 P ----------------
__global__ __launch_bounds__(256) void flash_mfma(
    const ushort* __restrict__ Qhi, const ushort* __restrict__ Qlo,
    const ushort* __restrict__ Khi, const ushort* __restrict__ Klo,
    const ushort* __restrict__ VThi, const ushort* __restrict__ VTlo,
    const float* __restrict__ SV,
    ushort* __restrict__ Ohi, ushort* __restrict__ Olo)
{
    __shared__ ushort Kh[4096], Kl[4096], Vh[4096], Vl[4096], Ph[4096];
    const int st = blockIdx.z, bh = blockIdx.y, b = bh>>3, h = bh&7;
    const int n0 = blockIdx.x<<6;
    const int tid = threadIdx.x, wave = tid>>6, lane = tid&63;
    const int fr = lane&15, fq = lane>>4;
    const float sc = SV[st*16 + bh];
    const size_t qb = (size_t)st*1048576 + (size_t)(b*1024 + n0)*512 + h*64;
    bf16x8 qfh[2], qfl[2];
    {
        const ushort* qph = Qhi + qb + (size_t)(wave*16 + fr)*512;
        const ushort* qpl = Qlo + qb + (size_t)(wave*16 + fr)*512;
        #pragma unroll
        for (int ks=0; ks<2; ++ks) {
            qfh[ks] = ldsb8(qph + ks*32 + fq*8);
            qfl[ks] = ldsb8(qpl + ks*32 + fq*8);
        }
    }
    f32x4 accO[4]; float lsum[4];
    #pragma unroll
    for (int i=0;i<4;++i){ accO[i]=(f32x4){0.f,0.f,0.f,0.f}; lsum[i]=0.f; }
    const size_t kb = (size_t)(b*TKV)*512 + h*64;
    const size_t vb = (size_t)(h*64)*VSTRIDE + b*TKV;
    for (int t0=0; t0<TKV; t0+=64) {
        #pragma unroll
        for (int it=0; it<2; ++it) {
            int r  = (wave<<4) + (it<<3) + (lane>>3);
            int lb = ((wave<<4) + (it<<3)) << 6;
            int gck = ((lane&7) ^ (r&7)) << 3;
            size_t gk = kb + (size_t)(t0+r)*512 + gck;
            size_t gv = vb + (size_t)r*VSTRIDE + t0 + gck;
            async16(Khi+gk, &Kh[lb]);
            async16(Klo+gk, &Kl[lb]);
            async16(VThi+gv, &Vh[lb]);
            async16(VTlo+gv, &Vl[lb]);
        }
        __syncthreads();
        f32x4 s[4];
        #pragma unroll
        for (int i=0;i<4;++i) s[i]=(f32x4){0.f,0.f,0.f,0.f};
        #pragma unroll
        for (int ks=0; ks<2; ++ks) {
            #pragma unroll
            for (int nf=0; nf<4; ++nf) {
                int r = nf*16+fr;
                int ko = (r<<6) + ((ks*32 + fq*8) ^ ((r&7)<<3));
                bf16x8 kh = ldsb8(&Kh[ko]), kl = ldsb8(&Kl[ko]);
                s[nf] = MFMA16(qfh[ks], kh, s[nf]);
                s[nf] = MFMA16(qfh[ks], kl, s[nf]);
                s[nf] = MFMA16(qfl[ks], kh, s[nf]);
            }
        }
        #pragma unroll
        for (int reg=0; reg<4; ++reg) {
            int prow = fq*4+reg;
            float psum = 0.f;
            #pragma unroll
            for (int nf=0;nf<4;++nf){
                float p = __expf(sc * s[nf][reg]);
                psum += p;
                int pidx = (wave<<10) + (prow<<6) + ((nf*16+fr) ^ ((prow&7)<<3));
                Ph[pidx] = f2bf(p);
            }
            lsum[reg] += psum;
        }
        #pragma unroll
        for (int ks=0; ks<2; ++ks) {
            int po = (wave<<10) + (fr<<6) + ((ks*32 + fq*8) ^ ((fr&7)<<3));
            bf16x8 ph = ldsb8(&Ph[po]);
            #pragma unroll
            for (int df=0; df<4; ++df) {
                int dd = df*16+fr;
                int vo = (dd<<6) + ((ks*32 + fq*8) ^ ((dd&7)<<3));
                bf16x8 vh = ldsb8(&Vh[vo]), vl = ldsb8(&Vl[vo]);
                accO[df] = MFMA16(ph, vh, accO[df]);
                accO[df] = MFMA16(ph, vl, accO[df]);
            }
        }
        __syncthreads();
    }
    #pragma unroll
    for (int reg=0; reg<4; ++reg) {
        #pragma unroll
        for (int m=1; m<16; m<<=1) lsum[reg] += __shfl_xor(lsum[reg], m, 16);
        float inv = 1.f/lsum[reg];
        int row = n0 + wave*16 + fq*4 + reg;
        #pragma unroll
        for (int df=0; df<4; ++df) {
            float v = accO[df][reg]*inv;
            size_t o = (size_t)st*1048576 + (size_t)(b*1024+row)*512 + h*64 + df*16 + fr;
            ushort hh = f2bf(v);
            Ohi[o] = hh; Olo[o] = f2bf(v-bf2f(hh));
        }
    }
}

// ---------------- workspace layout (byte offsets) ----------------
constexpr size_t OFF_CH  = 0;           // 8 doubles
constexpr size_t OFF_GK  = 64;          // 65536 f32
constexpr size_t OFF_SK  = 262208;      // 1024 f32
constexpr size_t OFF_GQ  = 266304;      // 3*65536 f32
constexpr size_t OFF_SQM = 1052736;     // 3*1024 f32
constexpr size_t OFF_SV  = 1065024;     // 48 f32
constexpr size_t ZERO_BYTES = 1065024;
constexpr size_t S0 = 1065472;          // W8: 8 x 1 MB (hi 512KB + lo 512KB)
constexpr size_t S1 = S0 + 8388608;     // WC weights -> ATT f32 -> {QB hilo, Kb hilo}
constexpr size_t S2 = S1 + 28311552;    // embC hilo -> KVS hilo
constexpr size_t S3 = S2 + 12582912;    // emb123 hilo
constexpr size_t S4 = S3 + 12582912;    // QCt hilo -> SIMhi (spills into S5)
constexpr size_t S5 = S4 + 12582912;    // KCt hilo -> SIMlo tail -> CTX hilo
constexpr size_t S6 = S5 + 12582912;    // VC hilo -> VT hilo
// total = S6 + 12582912 = 100,680,192 bytes (~96 MB)

extern "C" void kernel_launch(void* const* d_in, const int* in_sizes, int n_in,
                              void* d_out, int out_size, void* d_ws, size_t ws_size,
                              hipStream_t stream)
{
    const float* emb[3] = {(const float*)d_in[0], (const float*)d_in[1], (const float*)d_in[2]};
    const float* embC = (const float*)d_in[3];
    const float* WqF[3] = {(const float*)d_in[4], (const float*)d_in[5], (const float*)d_in[6]};
    const float* WkF  = (const float*)d_in[7];
    const float* WvF  = (const float*)d_in[8];
    const float* WCF[3] = {(const float*)d_in[9], (const float*)d_in[10], (const float*)d_in[11]};
    const float* WoF[3] = {(const float*)d_in[12], (const float*)d_in[13], (const float*)d_in[14]};
    float* out = (float*)d_out;
    char* ws = (char*)d_ws;

    auto U16 = [&](size_t off)->ushort* { return (ushort*)(ws + off); };
    auto F32 = [&](size_t off)->float*  { return (float*)(ws + off); };

    double* CH = (double*)(ws + OFF_CH);
    float *GK = F32(OFF_GK), *SK = F32(OFF_SK), *GQ = F32(OFF_GQ), *SQm = F32(OFF_SQM), *SV = F32(OFF_SV);

    auto W8hi = [&](int i){ return U16(S0 + (size_t)i*1048576); };
    auto W8lo = [&](int i){ return U16(S0 + (size_t)i*1048576 + 524288); };
    auto WChi = [&](int i){ return U16(S1 + (size_t)i*9437184); };
    auto WClo = [&](int i){ return U16(S1 + (size_t)i*9437184 + 4718592); };
    ushort *embChi=U16(S2), *embClo=U16(S2+6291456);
    ushort *embhi=U16(S3), *emblo=U16(S3+6291456);
    ushort *QCthi=U16(S4), *QCtlo=U16(S4+6291456);
    ushort *KCthi=U16(S5), *KCtlo=U16(S5+6291456);
    ushort *VChi=U16(S6), *VClo=U16(S6+6291456);
    float  *ATT = F32(S1);
    ushort *SIMhi=U16(S4), *SIMlo=U16(S4+9437184);
    ushort *KVShi=U16(S2), *KVSlo=U16(S2+6291456);
    ushort *QBhi=U16(S1), *QBlo=U16(S1+6291456);
    ushort *Kbhi=U16(S1+12582912), *Kblo=U16(S1+12582912+6291456);
    ushort *VThi=U16(S6), *VTlo=U16(S6+6291456);
    ushort *CTXhi=U16(S5), *CTXlo=U16(S5+6291456);

    dim3 blk(256);
    (void)hipMemsetAsync(d_ws, 0, ZERO_BYTES, stream);

    // fp32 -> bf16 hi/lo conversions
    CvtJobs J;
    J.src[0]=embC;   J.hi[0]=embChi; J.lo[0]=embClo; J.n[0]=2048*KVCH;
    for (int s=0;s<3;++s){ J.src[1+s]=emb[s]; J.hi[1+s]=embhi+(size_t)s*1048576; J.lo[1+s]=emblo+(size_t)s*1048576; J.n[1+s]=2*NTOK*EDIM; }
    for (int s=0;s<3;++s){ J.src[4+s]=WqF[s]; J.hi[4+s]=W8hi(s); J.lo[4+s]=W8lo(s); J.n[4+s]=EDIM*EDIM; }
    J.src[7]=WkF; J.hi[7]=W8hi(3); J.lo[7]=W8lo(3); J.n[7]=EDIM*EDIM;
    J.src[8]=WvF; J.hi[8]=W8hi(4); J.lo[8]=W8lo(4); J.n[8]=EDIM*EDIM;
    for (int s=0;s<3;++s){ J.src[9+s]=WCF[s]; J.hi[9+s]=WChi(s); J.lo[9+s]=WClo(s); J.n[9+s]=KVCH*KVCH; }
    for (int s=0;s<3;++s){ J.src[12+s]=WoF[s]; J.hi[12+s]=W8hi(5+s); J.lo[12+s]=W8lo(5+s); J.n[12+s]=EDIM*EDIM; }
    cvt_hilo<<<dim3(3072, NCVT), blk, 0, stream>>>(J);

    GemmDesc Z{}; Z.zmod = 1;

    // L3: channel projections — QK transposed (z=w*2+b) + V natural (z=b)
    {
        GemmDesc dq = Z;
        dq.Ahi=embChi; dq.Alo=embClo; dq.Bhi=WChi(0); dq.Blo=WClo(0);
        dq.Cthi=QCthi; dq.Ctlo=QCtlo;
        dq.K=KVCH; dq.lda=KVCH; dq.ldb=KVCH; dq.ldct=NTOK;
        dq.zmod=2; dq.sA0=0; dq.sA1=(long)NTOK*KVCH; dq.sB0=4718592; dq.sB1=0;
        dq.sC0=6291456; dq.sC1=(long)KVCH*NTOK;
        GemmDesc dv = Z;
        dv.Ahi=embChi; dv.Alo=embClo; dv.Bhi=WChi(2); dv.Blo=WClo(2);
        dv.Chi=VChi; dv.Clo=VClo;
        dv.K=KVCH; dv.lda=KVCH; dv.ldb=KVCH; dv.ldc=KVCH;
        dv.sA0=(long)NTOK*KVCH; dv.sC0=(long)NTOK*KVCH;
        mgemmF<<<dim3(576), blk, 0, stream>>>(dq, dv, 384, 12, 8, 12, 8);
    }
    // L4: ATT[b] = QC^T KC (+ mean/var stats in epilogue)
    {
        GemmDesc da = Z;
        da.Ahi=QCthi; da.Alo=QCtlo; da.Bhi=KCthi; da.Blo=KCtlo;
        da.Cf=ATT; da.stats=CH;
        da.K=NTOK; da.lda=NTOK; da.ldb=NTOK; da.ldc=KVCH;
        da.sA0=(long)KVCH*NTOK; da.sB0=(long)KVCH*NTOK; da.sC0=(long)KVCH*KVCH;
        mgemmF<<<dim3(288), blk, 0, stream>>>(da, da, 288, 12, 12, 1, 1);
    }
    chan_softmax<<<dim3(1536,2), blk, 0, stream>>>(ATT, CH, SIMhi, SIMlo);
    // L6: KVS (z=b*3+j) + Q projections (z=stream)
    {
        GemmDesc dk = Z;
        dk.Ahi=VChi; dk.Alo=VClo; dk.Bhi=SIMhi; dk.Blo=SIMlo;
        dk.Chi=KVShi; dk.Clo=KVSlo;
        dk.K=KVCH; dk.lda=KVCH; dk.ldb=KVCH; dk.ldc=EDIM;
        dk.zmod=3; dk.sA0=(long)NTOK*KVCH; dk.sA1=0;
        dk.sB0=(long)KVCH*KVCH; dk.sB1=(long)EDIM*KVCH;
        dk.sC0=(long)TKV*EDIM; dk.sC1=(long)NTOK*EDIM;
        GemmDesc dqp = Z;
        dqp.Ahi=embhi; dqp.Alo=emblo; dqp.Bhi=W8hi(0); dqp.Blo=W8lo(0);
        dqp.Chi=QBhi; dqp.Clo=QBlo;
        dqp.K=EDIM; dqp.lda=EDIM; dqp.ldb=EDIM; dqp.ldc=EDIM;
        dqp.sA0=1048576; dqp.sB0=524288; dqp.sC0=1048576;
        mgemmF<<<dim3(384), blk, 0, stream>>>(dk, dqp, 192, 4, 8, 4, 16);
    }
    // L7: K projection (natural) + V projection (transposed -> VT directly)
    {
        GemmDesc dkp = Z;
        dkp.Ahi=KVShi; dkp.Alo=KVSlo; dkp.Bhi=W8hi(3); dkp.Blo=W8lo(3);
        dkp.Chi=Kbhi; dkp.Clo=Kblo;
        dkp.K=EDIM; dkp.lda=EDIM; dkp.ldb=EDIM; dkp.ldc=EDIM;
        GemmDesc dvp = Z;
        dvp.Ahi=KVShi; dvp.Alo=KVSlo; dvp.Bhi=W8hi(4); dvp.Blo=W8lo(4);
        dvp.Cthi=VThi; dvp.Ctlo=VTlo;
        dvp.K=EDIM; dvp.lda=EDIM; dvp.ldb=EDIM; dvp.ldct=VSTRIDE;
        mgemmF<<<dim3(384), blk, 0, stream>>>(dkp, dvp, 192, 4, 48, 4, 48);
    }
    gram4<<<dim3(16,8,4), blk, 0, stream>>>(Kbhi, Kblo, QBhi, QBlo, GK, SK, GQ, SQm);
    spatial_scale<<<dim3(16,3), blk, 0, stream>>>(GQ, GK, SQm, SK, SV);
    flash_mfma<<<dim3(16,16,3), blk, 0, stream>>>(QBhi, QBlo, Kbhi, Kblo, VThi, VTlo, SV, CTXhi, CTXlo);
    // L11: output projections
    {
        GemmDesc dop = Z;
        dop.Ahi=CTXhi; dop.Alo=CTXlo; dop.Bhi=W8hi(5); dop.Blo=W8lo(5);
        dop.Cf=out;
        dop.K=EDIM; dop.lda=EDIM; dop.ldb=EDIM; dop.ldc=EDIM;
        dop.sA0=1048576; dop.sB0=524288; dop.sC0=1048576;
        mgemmF<<<dim3(192), blk, 0, stream>>>(dop, dop, 192, 4, 16, 1, 1);
    }
}